// Round 1
// baseline (303.054 us; speedup 1.0000x reference)
//
#include <hip/hip_runtime.h>
#include <stdint.h>

typedef unsigned short u16;
typedef short short8 __attribute__((ext_vector_type(8)));
typedef float f32x4 __attribute__((ext_vector_type(4)));

#define SCALE 0.125f

__device__ __forceinline__ u16 f2bf(float f) {
  union { float f; uint32_t u; } v;
  v.f = f;
  uint32_t u = v.u;
  u += 0x7FFFu + ((u >> 16) & 1u);   // RNE; inputs are finite
  return (u16)(u >> 16);
}

// ---------------- prep kernels ----------------

__global__ __launch_bounds__(256) void k_cvt_x(const float* __restrict__ x,
                                               u16* __restrict__ xb, int n4) {
  int g = blockIdx.x * 256 + threadIdx.x;
  if (g >= n4) return;
  float4 v = ((const float4*)x)[g];
  ushort4 o;
  o.x = f2bf(v.x); o.y = f2bf(v.y); o.z = f2bf(v.z); o.w = f2bf(v.w);
  ((ushort4*)xb)[g] = o;
}

// dst[c][r] = bf16(src[r][c]);  R,C multiples of 32
__global__ __launch_bounds__(256) void k_transpose_bf(const float* __restrict__ src,
                                                      u16* __restrict__ dst, int R, int C) {
  __shared__ float t[32][33];
  int c0 = blockIdx.x * 32, r0 = blockIdx.y * 32;
  int tx = threadIdx.x, ty = threadIdx.y;
#pragma unroll
  for (int i = 0; i < 4; ++i)
    t[ty + 8 * i][tx] = src[(size_t)(r0 + ty + 8 * i) * C + c0 + tx];
  __syncthreads();
#pragma unroll
  for (int i = 0; i < 4; ++i)
    dst[(size_t)(c0 + ty + 8 * i) * R + r0 + tx] = f2bf(t[tx][ty + 8 * i]);
}

// pack int mask (1 = masked out) into bit words: bit j of word w = mask[32w+j]
__global__ __launch_bounds__(256) void k_mask_pack(const int* __restrict__ m,
                                                   uint32_t* __restrict__ w, int n) {
  int g = blockIdx.x * 256 + threadIdx.x;
  if (g >= n) return;
  unsigned long long bal = __ballot(m[g] != 0);
  int lane = threadIdx.x & 63;
  if (lane == 0) w[g >> 5] = (uint32_t)bal;
  else if (lane == 32) w[g >> 5] = (uint32_t)(bal >> 32);
}

// ---------------- GEMM core (128x128 tile, BK=32, 4 waves 2x2) ----------------
// A: [M][K] bf16 row-major.  Bt: [N][K] bf16 row-major (i.e. B transposed).
// acc[mi][ni] is the wave's 64x64 sub-tile as 4x4 MFMA 16x16 fragments.
// LDS XOR swizzle: 64B rows of 4 16B chunks, chunk c stored at c ^ ((row>>1)&3)
// -> fragment reads are ~2-way bank aliasing (free).

__device__ __forceinline__ void gemm_core(const u16* __restrict__ A,
                                          const u16* __restrict__ Bt,
                                          int K, int m0, int n0,
                                          f32x4 (&acc)[4][4], char* lds) {
  const int t = threadIdx.x;
  const int l = t & 63;
  const int w = t >> 6;
  const int wm = w >> 1, wn = w & 1;
  const int lr = l & 15, lg = l >> 4;
  char* ldsA = lds;
  char* ldsB = lds + 8192;
  const int nk = K >> 5;
#pragma unroll 1
  for (int kt = 0; kt < nk; ++kt) {
    const int k0 = kt << 5;
#pragma unroll
    for (int i = 0; i < 2; ++i) {
      int q = t + (i << 8);
      int row = q >> 2, c = q & 3;
      int sw = row * 64 + ((c ^ ((row >> 1) & 3)) << 4);
      *(uint4*)(ldsA + sw) = *(const uint4*)(A + (size_t)(m0 + row) * K + k0 + c * 8);
      *(uint4*)(ldsB + sw) = *(const uint4*)(Bt + (size_t)(n0 + row) * K + k0 + c * 8);
    }
    __syncthreads();
    short8 af[4], bfr[4];
#pragma unroll
    for (int mi = 0; mi < 4; ++mi) {
      int row = wm * 64 + mi * 16 + lr;
      af[mi] = *(const short8*)(ldsA + row * 64 + ((lg ^ ((row >> 1) & 3)) << 4));
    }
#pragma unroll
    for (int ni = 0; ni < 4; ++ni) {
      int row = wn * 64 + ni * 16 + lr;
      bfr[ni] = *(const short8*)(ldsB + row * 64 + ((lg ^ ((row >> 1) & 3)) << 4));
    }
#pragma unroll
    for (int mi = 0; mi < 4; ++mi)
#pragma unroll
      for (int ni = 0; ni < 4; ++ni)
        acc[mi][ni] = __builtin_amdgcn_mfma_f32_16x16x32_bf16(af[mi], bfr[ni], acc[mi][ni], 0, 0, 0);
    __syncthreads();
  }
}

// GEMM1: qkv = x @ W_qkv, scatter epilogue into Q [b,h,n,d], K [b,h,n,d], VT [b,h,d,n]
__global__ __launch_bounds__(256) void k_gemm_qkv(const u16* __restrict__ xb,
                                                  const u16* __restrict__ wqT,
                                                  u16* __restrict__ Qb,
                                                  u16* __restrict__ Kb,
                                                  u16* __restrict__ VT) {
  __shared__ char lds[16384] __attribute__((aligned(16)));
  int n0 = blockIdx.x * 128, m0 = blockIdx.y * 128;
  f32x4 acc[4][4] = {};
  gemm_core(xb, wqT, 1024, m0, n0, acc, lds);
  const int l = threadIdx.x & 63, w = threadIdx.x >> 6;
  const int wm = w >> 1, wn = w & 1;
  const int lr = l & 15, lg = l >> 4;
#pragma unroll
  for (int mi = 0; mi < 4; ++mi)
#pragma unroll
    for (int ni = 0; ni < 4; ++ni)
#pragma unroll
      for (int r = 0; r < 4; ++r) {
        int m = m0 + wm * 64 + mi * 16 + lg * 4 + r;
        int n = n0 + wn * 64 + ni * 16 + lr;
        int b = m >> 11, seq = m & 2047;
        u16 v = f2bf(acc[mi][ni][r]);
        if (n < 1024) {
          Qb[((size_t)((b << 4) + (n >> 6)) * 2048 + seq) * 64 + (n & 63)] = v;
        } else if (n < 2048) {
          int nn = n - 1024;
          Kb[((size_t)((b << 4) + (nn >> 6)) * 2048 + seq) * 64 + (nn & 63)] = v;
        } else {
          int nn = n - 2048;
          VT[((size_t)((b << 4) + (nn >> 6)) * 64 + (nn & 63)) * 2048 + seq] = v;
        }
      }
}

// GEMM2: out = AO @ W_out + b_out  (fp32 output)
__global__ __launch_bounds__(256) void k_gemm_out(const u16* __restrict__ ao,
                                                  const u16* __restrict__ woT,
                                                  const float* __restrict__ bias,
                                                  float* __restrict__ out) {
  __shared__ char lds[16384] __attribute__((aligned(16)));
  int n0 = blockIdx.x * 128, m0 = blockIdx.y * 128;
  f32x4 acc[4][4] = {};
  gemm_core(ao, woT, 1024, m0, n0, acc, lds);
  const int l = threadIdx.x & 63, w = threadIdx.x >> 6;
  const int wm = w >> 1, wn = w & 1;
  const int lr = l & 15, lg = l >> 4;
#pragma unroll
  for (int mi = 0; mi < 4; ++mi)
#pragma unroll
    for (int ni = 0; ni < 4; ++ni)
#pragma unroll
      for (int r = 0; r < 4; ++r) {
        int m = m0 + wm * 64 + mi * 16 + lg * 4 + r;
        int n = n0 + wn * 64 + ni * 16 + lr;
        out[(size_t)m * 1024 + n] = acc[mi][ni][r] + bias[n];
      }
}

// ---------------- flash attention ----------------
// grid = B*H*(N/128) blocks; 4 waves; wave owns 32 Q rows; KV tiles of 32.
// Q [b,h,n,64], K [b,h,n,64], VT [b,h,64,n] bf16; maskw bit=1 -> masked.
__global__ __launch_bounds__(256) void k_attn(const u16* __restrict__ Qg,
                                              const u16* __restrict__ Kg,
                                              const u16* __restrict__ Vg,
                                              const uint32_t* __restrict__ maskw,
                                              u16* __restrict__ AO) {
  __shared__ char lds[16384] __attribute__((aligned(16)));
  // [0,4096): K tile 32x128B (chunk sw: c ^ (row&7))
  // [4096,8192): VT tile 64x64B (chunk sw: c ^ ((row>>1)&3))
  // [8192+w*2048): per-wave P tile 32x64B (chunk sw: c ^ ((row>>1)&3))
  const int bid = blockIdx.x;
  const int qt = bid & 15;
  const int h = (bid >> 4) & 15;
  const int b = bid >> 8;
  const int bh = (b << 4) + h;
  const int t = threadIdx.x, l = t & 63, w = t >> 6;
  const int lr = l & 15, lg = l >> 4;

  const u16* Qp = Qg + (size_t)bh * 2048 * 64;
  const u16* Kp = Kg + (size_t)bh * 2048 * 64;
  const u16* Vp = Vg + (size_t)bh * 64 * 2048;
  const int qrow0 = qt * 128 + w * 32;
  const uint32_t* mbase = maskw + (size_t)b * 2048 * 64 + (size_t)qrow0 * 64;

  short8 qf[2][2];
#pragma unroll
  for (int mb = 0; mb < 2; ++mb)
#pragma unroll
    for (int s = 0; s < 2; ++s)
      qf[mb][s] = *(const short8*)(Qp + (size_t)(qrow0 + mb * 16 + lr) * 64 + s * 32 + lg * 8);

  f32x4 O[2][4] = {};
  float mrun[2][4], lrun[2][4];
#pragma unroll
  for (int mb = 0; mb < 2; ++mb)
#pragma unroll
    for (int r = 0; r < 4; ++r) { mrun[mb][r] = -1e30f; lrun[mb][r] = 0.f; }

  char* ldsP = lds + 8192 + w * 2048;

#pragma unroll 1
  for (int kv = 0; kv < 2048; kv += 32) {
    {
      int row = t >> 3, c = t & 7;
      *(uint4*)(lds + row * 128 + ((c ^ (row & 7)) << 4)) =
          *(const uint4*)(Kp + (size_t)(kv + row) * 64 + c * 8);
      int vr = t >> 2, vc = t & 3;
      *(uint4*)(lds + 4096 + vr * 64 + ((vc ^ ((vr >> 1) & 3)) << 4)) =
          *(const uint4*)(Vp + (size_t)vr * 2048 + kv + vc * 8);
    }
    __syncthreads();

    // S = Q K^T  (S^... C layout: row=q-row, col=kv col)
    f32x4 sacc[2][2] = {};
#pragma unroll
    for (int s = 0; s < 2; ++s) {
      short8 kf[2];
#pragma unroll
      for (int nb = 0; nb < 2; ++nb) {
        int krow = nb * 16 + lr;
        kf[nb] = *(const short8*)(lds + krow * 128 + (((4 * s + lg) ^ (krow & 7)) << 4));
      }
#pragma unroll
      for (int mb = 0; mb < 2; ++mb)
#pragma unroll
        for (int nb = 0; nb < 2; ++nb)
          sacc[mb][nb] = __builtin_amdgcn_mfma_f32_16x16x32_bf16(qf[mb][s], kf[nb], sacc[mb][nb], 0, 0, 0);
    }

    const int kvt = kv >> 5;
#pragma unroll
    for (int mb = 0; mb < 2; ++mb) {
#pragma unroll
      for (int r = 0; r < 4; ++r) {
        int qi = mb * 16 + lg * 4 + r;
        uint32_t mw = mbase[(size_t)qi * 64 + kvt];
        float s0 = sacc[mb][0][r] * SCALE;
        float s1 = sacc[mb][1][r] * SCALE;
        if ((mw >> lr) & 1u) s0 = -1e30f;
        if ((mw >> (16 + lr)) & 1u) s1 = -1e30f;
        float mx = fmaxf(s0, s1);
        mx = fmaxf(mx, __shfl_xor(mx, 1));
        mx = fmaxf(mx, __shfl_xor(mx, 2));
        mx = fmaxf(mx, __shfl_xor(mx, 4));
        mx = fmaxf(mx, __shfl_xor(mx, 8));
        float mold = mrun[mb][r];
        float mnew = fmaxf(mold, mx);
        float corr = __expf(mold - mnew);
        float p0 = (s0 < -1e29f) ? 0.f : __expf(s0 - mnew);
        float p1 = (s1 < -1e29f) ? 0.f : __expf(s1 - mnew);
        float ps = p0 + p1;
        ps += __shfl_xor(ps, 1);
        ps += __shfl_xor(ps, 2);
        ps += __shfl_xor(ps, 4);
        ps += __shfl_xor(ps, 8);
        lrun[mb][r] = lrun[mb][r] * corr + ps;
        mrun[mb][r] = mnew;
#pragma unroll
        for (int db = 0; db < 4; ++db) O[mb][db][r] *= corr;
        // stash P (bf16) in per-wave swizzled LDS tile
        int c0 = lr >> 3, c1 = 2 + (lr >> 3);
        int fq = (qi >> 1) & 3;
        *(u16*)(ldsP + qi * 64 + ((c0 ^ fq) << 4) + (lr & 7) * 2) = f2bf(p0);
        *(u16*)(ldsP + qi * 64 + ((c1 ^ fq) << 4) + (lr & 7) * 2) = f2bf(p1);
      }
    }

    // PV: O += P @ V
    short8 vf[4];
#pragma unroll
    for (int db = 0; db < 4; ++db) {
      int vrow = db * 16 + lr;
      vf[db] = *(const short8*)(lds + 4096 + vrow * 64 + ((lg ^ ((vrow >> 1) & 3)) << 4));
    }
#pragma unroll
    for (int mb = 0; mb < 2; ++mb) {
      int prow = mb * 16 + lr;
      short8 pf = *(const short8*)(ldsP + prow * 64 + ((lg ^ ((prow >> 1) & 3)) << 4));
#pragma unroll
      for (int db = 0; db < 4; ++db)
        O[mb][db] = __builtin_amdgcn_mfma_f32_16x16x32_bf16(pf, vf[db], O[mb][db], 0, 0, 0);
    }
    __syncthreads();
  }

#pragma unroll
  for (int mb = 0; mb < 2; ++mb)
#pragma unroll
    for (int r = 0; r < 4; ++r) {
      int qi = mb * 16 + lg * 4 + r;
      float inv = 1.0f / fmaxf(lrun[mb][r], 1e-20f);
      size_t orow = (size_t)b * 2048 + qrow0 + qi;
#pragma unroll
      for (int db = 0; db < 4; ++db)
        AO[orow * 1024 + h * 64 + db * 16 + lr] = f2bf(O[mb][db][r] * inv);
    }
}

// ---------------- launch ----------------

extern "C" void kernel_launch(void* const* d_in, const int* in_sizes, int n_in,
                              void* d_out, int out_size, void* d_ws, size_t ws_size,
                              hipStream_t stream) {
  const float* x = (const float*)d_in[0];
  const int* mask = (const int*)d_in[1];
  const float* Wqkv = (const float*)d_in[2];
  const float* Wout = (const float*)d_in[3];
  const float* bout = (const float*)d_in[4];
  float* out = (float*)d_out;
  char* ws = (char*)d_ws;
  const size_t MB = 1u << 20;
  if (ws_size < 49 * MB) return;

  u16* xb = (u16*)(ws);                 // 8 MB  [4096][1024]
  u16* wqT = (u16*)(ws + 8 * MB);       // 6 MB  [3072][1024]
  u16* woT = (u16*)(ws + 14 * MB);      // 2 MB  [1024][1024]
  uint32_t* mw = (uint32_t*)(ws + 16 * MB); // 1 MB [B][2048][64]
  u16* Qb = (u16*)(ws + 17 * MB);       // 8 MB  [B,H,2048,64]
  u16* Kb = (u16*)(ws + 25 * MB);       // 8 MB  [B,H,2048,64]
  u16* VT = (u16*)(ws + 33 * MB);       // 8 MB  [B,H,64,2048]
  u16* AO = (u16*)(ws + 41 * MB);       // 8 MB  [4096][1024]

  k_cvt_x<<<4096, 256, 0, stream>>>(x, xb, 1048576);
  k_transpose_bf<<<dim3(96, 32), dim3(32, 8), 0, stream>>>(Wqkv, wqT, 1024, 3072);
  k_transpose_bf<<<dim3(32, 32), dim3(32, 8), 0, stream>>>(Wout, woT, 1024, 1024);
  k_mask_pack<<<32768, 256, 0, stream>>>(mask, mw, 8388608);
  k_gemm_qkv<<<dim3(24, 32), 256, 0, stream>>>(xb, wqT, Qb, Kb, VT);
  k_attn<<<512, 256, 0, stream>>>(Qb, Kb, VT, mw, AO);
  k_gemm_out<<<dim3(8, 32), 256, 0, stream>>>(AO, woT, bout, out);
}

// Round 2
// 193.603 us; speedup vs baseline: 1.5653x; 1.5653x over previous
//
#include <hip/hip_runtime.h>
#include <stdint.h>

typedef unsigned short u16;
typedef short short8 __attribute__((ext_vector_type(8)));
typedef float f32x4 __attribute__((ext_vector_type(4)));
typedef float f32x16 __attribute__((ext_vector_type(16)));
typedef unsigned int uint2v __attribute__((ext_vector_type(2)));

#define SCALE 0.125f
#define K2E 0.18033688011112042f  /* 0.125 * log2(e) */

__device__ __forceinline__ u16 f2bf(float f) {
  union { float f; uint32_t u; } v;
  v.f = f;
  uint32_t u = v.u;
  u += 0x7FFFu + ((u >> 16) & 1u);   // RNE; inputs are finite
  return (u16)(u >> 16);
}

__device__ __forceinline__ uint32_t cvtpk(float lo, float hi) {
  uint32_t r;
  asm("v_cvt_pk_bf16_f32 %0, %1, %2" : "=v"(r) : "v"(lo), "v"(hi));
  return r;
}

__device__ __forceinline__ float exp2a(float x) {
  float r;
  asm("v_exp_f32 %0, %1" : "=v"(r) : "v"(x));
  return r;
}

__device__ __forceinline__ float row_max2(float x) {
  uint2v r = __builtin_amdgcn_permlane32_swap(__float_as_uint(x), __float_as_uint(x), false, false);
  return fmaxf(__uint_as_float(r.x), __uint_as_float(r.y));
}

__device__ __forceinline__ float row_add2(float x) {
  uint2v r = __builtin_amdgcn_permlane32_swap(__float_as_uint(x), __float_as_uint(x), false, false);
  return __uint_as_float(r.x) + __uint_as_float(r.y);
}

__device__ __forceinline__ void gld_lds16(const u16* src, char* dst) {
  __builtin_amdgcn_global_load_lds((const __attribute__((address_space(1))) void*)src,
                                   (__attribute__((address_space(3))) void*)dst, 16, 0, 0);
}

// pack one 32x32 S^T fragment (16 f32 p-values) into two PV B-fragments (kv-chunks of 16)
__device__ __forceinline__ void pack_frags(const f32x16& v, short8& fa, short8& fb) {
  union U { uint32_t w[4]; short8 v8; };
  uint32_t X0 = cvtpk(v[0], v[1]),   X1 = cvtpk(v[2], v[3]);
  uint32_t Y0 = cvtpk(v[4], v[5]),   Y1 = cvtpk(v[6], v[7]);
  uint32_t X2 = cvtpk(v[8], v[9]),   X3 = cvtpk(v[10], v[11]);
  uint32_t Y2 = cvtpk(v[12], v[13]), Y3 = cvtpk(v[14], v[15]);
  uint2v r0 = __builtin_amdgcn_permlane32_swap(X0, Y0, false, false);
  uint2v r1 = __builtin_amdgcn_permlane32_swap(X1, Y1, false, false);
  uint2v r2 = __builtin_amdgcn_permlane32_swap(X2, Y2, false, false);
  uint2v r3 = __builtin_amdgcn_permlane32_swap(X3, Y3, false, false);
  U ua; ua.w[0] = r0.x; ua.w[1] = r1.x; ua.w[2] = r0.y; ua.w[3] = r1.y; fa = ua.v8;
  U ub; ub.w[0] = r2.x; ub.w[1] = r3.x; ub.w[2] = r2.y; ub.w[3] = r3.y; fb = ub.v8;
}

// ---------------- prep kernels ----------------

__global__ __launch_bounds__(256) void k_cvt_x(const float* __restrict__ x,
                                               u16* __restrict__ xb, int n4) {
  int g = blockIdx.x * 256 + threadIdx.x;
  if (g >= n4) return;
  float4 v = ((const float4*)x)[g];
  ushort4 o;
  o.x = f2bf(v.x); o.y = f2bf(v.y); o.z = f2bf(v.z); o.w = f2bf(v.w);
  ((ushort4*)xb)[g] = o;
}

__global__ __launch_bounds__(256) void k_transpose_bf(const float* __restrict__ src,
                                                      u16* __restrict__ dst, int R, int C) {
  __shared__ float t[32][33];
  int c0 = blockIdx.x * 32, r0 = blockIdx.y * 32;
  int tx = threadIdx.x, ty = threadIdx.y;
#pragma unroll
  for (int i = 0; i < 4; ++i)
    t[ty + 8 * i][tx] = src[(size_t)(r0 + ty + 8 * i) * C + c0 + tx];
  __syncthreads();
#pragma unroll
  for (int i = 0; i < 4; ++i)
    dst[(size_t)(c0 + ty + 8 * i) * R + r0 + tx] = f2bf(t[tx][ty + 8 * i]);
}

__global__ __launch_bounds__(256) void k_mask_pack(const int* __restrict__ m,
                                                   uint32_t* __restrict__ w, int n) {
  int g = blockIdx.x * 256 + threadIdx.x;
  if (g >= n) return;
  unsigned long long bal = __ballot(m[g] != 0);
  int lane = threadIdx.x & 63;
  if (lane == 0) w[g >> 5] = (uint32_t)bal;
  else if (lane == 32) w[g >> 5] = (uint32_t)(bal >> 32);
}

// ---------------- GEMM core (unchanged from R0) ----------------

__device__ __forceinline__ void gemm_core(const u16* __restrict__ A,
                                          const u16* __restrict__ Bt,
                                          int K, int m0, int n0,
                                          f32x4 (&acc)[4][4], char* lds) {
  const int t = threadIdx.x;
  const int l = t & 63;
  const int w = t >> 6;
  const int wm = w >> 1, wn = w & 1;
  const int lr = l & 15, lg = l >> 4;
  char* ldsA = lds;
  char* ldsB = lds + 8192;
  const int nk = K >> 5;
#pragma unroll 1
  for (int kt = 0; kt < nk; ++kt) {
    const int k0 = kt << 5;
#pragma unroll
    for (int i = 0; i < 2; ++i) {
      int q = t + (i << 8);
      int row = q >> 2, c = q & 3;
      int sw = row * 64 + ((c ^ ((row >> 1) & 3)) << 4);
      *(uint4*)(ldsA + sw) = *(const uint4*)(A + (size_t)(m0 + row) * K + k0 + c * 8);
      *(uint4*)(ldsB + sw) = *(const uint4*)(Bt + (size_t)(n0 + row) * K + k0 + c * 8);
    }
    __syncthreads();
    short8 af[4], bfr[4];
#pragma unroll
    for (int mi = 0; mi < 4; ++mi) {
      int row = wm * 64 + mi * 16 + lr;
      af[mi] = *(const short8*)(ldsA + row * 64 + ((lg ^ ((row >> 1) & 3)) << 4));
    }
#pragma unroll
    for (int ni = 0; ni < 4; ++ni) {
      int row = wn * 64 + ni * 16 + lr;
      bfr[ni] = *(const short8*)(ldsB + row * 64 + ((lg ^ ((row >> 1) & 3)) << 4));
    }
#pragma unroll
    for (int mi = 0; mi < 4; ++mi)
#pragma unroll
      for (int ni = 0; ni < 4; ++ni)
        acc[mi][ni] = __builtin_amdgcn_mfma_f32_16x16x32_bf16(af[mi], bfr[ni], acc[mi][ni], 0, 0, 0);
    __syncthreads();
  }
}

__global__ __launch_bounds__(256) void k_gemm_qkv(const u16* __restrict__ xb,
                                                  const u16* __restrict__ wqT,
                                                  u16* __restrict__ Qb,
                                                  u16* __restrict__ Kb,
                                                  u16* __restrict__ VT) {
  __shared__ char lds[16384] __attribute__((aligned(16)));
  int n0 = blockIdx.x * 128, m0 = blockIdx.y * 128;
  f32x4 acc[4][4] = {};
  gemm_core(xb, wqT, 1024, m0, n0, acc, lds);
  const int l = threadIdx.x & 63, w = threadIdx.x >> 6;
  const int wm = w >> 1, wn = w & 1;
  const int lr = l & 15, lg = l >> 4;
#pragma unroll
  for (int mi = 0; mi < 4; ++mi)
#pragma unroll
    for (int ni = 0; ni < 4; ++ni)
#pragma unroll
      for (int r = 0; r < 4; ++r) {
        int m = m0 + wm * 64 + mi * 16 + lg * 4 + r;
        int n = n0 + wn * 64 + ni * 16 + lr;
        int b = m >> 11, seq = m & 2047;
        u16 v = f2bf(acc[mi][ni][r]);
        if (n < 1024) {
          Qb[((size_t)((b << 4) + (n >> 6)) * 2048 + seq) * 64 + (n & 63)] = v;
        } else if (n < 2048) {
          int nn = n - 1024;
          Kb[((size_t)((b << 4) + (nn >> 6)) * 2048 + seq) * 64 + (nn & 63)] = v;
        } else {
          int nn = n - 2048;
          VT[((size_t)((b << 4) + (nn >> 6)) * 64 + (nn & 63)) * 2048 + seq] = v;
        }
      }
}

__global__ __launch_bounds__(256) void k_gemm_out(const u16* __restrict__ ao,
                                                  const u16* __restrict__ woT,
                                                  const float* __restrict__ bias,
                                                  float* __restrict__ out) {
  __shared__ char lds[16384] __attribute__((aligned(16)));
  int n0 = blockIdx.x * 128, m0 = blockIdx.y * 128;
  f32x4 acc[4][4] = {};
  gemm_core(ao, woT, 1024, m0, n0, acc, lds);
  const int l = threadIdx.x & 63, w = threadIdx.x >> 6;
  const int wm = w >> 1, wn = w & 1;
  const int lr = l & 15, lg = l >> 4;
#pragma unroll
  for (int mi = 0; mi < 4; ++mi)
#pragma unroll
    for (int ni = 0; ni < 4; ++ni)
#pragma unroll
      for (int r = 0; r < 4; ++r) {
        int m = m0 + wm * 64 + mi * 16 + lg * 4 + r;
        int n = n0 + wn * 64 + ni * 16 + lr;
        out[(size_t)m * 1024 + n] = acc[mi][ni][r] + bias[n];
      }
}

// ---------------- flash attention (swapped-QK, in-register softmax) ----------------
// grid = B*H*(N/128); 4 waves; wave owns 32 q rows (q = q0w + lane&31, both halves same q).
// KVBLK=64. K tile [64][64] bf16, V^T tile [64][64] bf16 in LDS, XOR-swizzled
// (8-elem chunk c at c^(row&7)), staged via global_load_lds w/ pre-swizzled source.
// S^T[kv][q] = mfma_32x32x16(K, Q): lane holds 32 p-values of ONE q row (half; pair
// lane l/l+32 holds other half). Softmax in-register: 31 fmax + permlane32_swap.
// PV swapped: O^T[d][q] = mfma(V^T, P^T) keeps q lane-local; P^T frags built via
// cvt_pk_bf16 + permlane32_swap (T12). Defer-max THR=8 (log2) (T13).
__global__ __launch_bounds__(256) void k_attn(const u16* __restrict__ Qg,
                                              const u16* __restrict__ Kg,
                                              const u16* __restrict__ Vg,
                                              const uint32_t* __restrict__ maskw,
                                              u16* __restrict__ AO) {
  __shared__ char lds[32768] __attribute__((aligned(128)));
  const int bid = blockIdx.x;
  const int qt = bid & 15;
  const int hd = (bid >> 4) & 15;
  const int b = bid >> 8;
  const int bh = (b << 4) + hd;
  const int tx = threadIdx.x, l = tx & 63, w = tx >> 6;
  const int l31 = l & 31, h = l >> 5;
  const int hx4 = (h ^ (l & 7)) << 4;          // read-side swizzle term
  const int sc8 = ((l & 7) ^ (l >> 3)) << 3;   // staging source chunk (elements)
  const int lr8 = l >> 3;

  const u16* Qp = Qg + (size_t)bh * 2048 * 64;
  const u16* Kp = Kg + (size_t)bh * 2048 * 64;
  const u16* Vp = Vg + (size_t)bh * 64 * 2048;
  const int q0w = qt * 128 + w * 32;
  const int q = q0w + l31;
  const uint32_t* mrow = maskw + ((size_t)(b << 11) + q) * 64;

  // Q fragments (B-operand): qf[s] = Q[q][16s + 8h + 0..7]
  short8 qf[4];
#pragma unroll
  for (int s = 0; s < 4; ++s)
    qf[s] = *(const short8*)(Qp + (size_t)q * 64 + s * 16 + h * 8);

  f32x16 Oa[2] = {};
  float m_run = -1e30f, l_run = 0.f;

#define STAGE(BSEL, TT)                                                            \
  {                                                                                \
    const int kv0_ = (TT) << 6;                                                    \
    char* base_ = lds + (BSEL) * 16384;                                            \
    _Pragma("unroll")                                                              \
    for (int i_ = 0; i_ < 2; ++i_) {                                               \
      const int rr_ = 16 * w + 8 * i_ + lr8;                                       \
      gld_lds16(Kp + (size_t)(kv0_ + rr_) * 64 + sc8, base_ + (16 * w + 8 * i_) * 128); \
      gld_lds16(Vp + (size_t)rr_ * 2048 + kv0_ + sc8, base_ + 8192 + (16 * w + 8 * i_) * 128); \
    }                                                                              \
  }

  STAGE(0, 0);
  uint2v mmc = *(const uint2v*)(mrow);

#pragma unroll 1
  for (int tt = 0; tt < 32; ++tt) {
    __syncthreads();                       // stage(tt) landed; compute(tt-1) done
    if (tt + 1 < 32) STAGE((tt + 1) & 1, tt + 1);
    const int tn = (tt + 1 < 32) ? (tt + 1) : 31;
    uint2v mmn = *(const uint2v*)(mrow + 2 * tn);

    const char* kbase = lds + (tt & 1) * 16384 + l31 * 128;
    const char* vbase = kbase + 8192;

    // S^T = K @ Q^T
    f32x16 sa = {}, sb = {};
    __builtin_amdgcn_s_setprio(1);
#pragma unroll
    for (int s = 0; s < 4; ++s) {
      short8 k0 = *(const short8*)(kbase + ((s << 5) ^ hx4));
      short8 k1 = *(const short8*)(kbase + 4096 + ((s << 5) ^ hx4));
      sa = __builtin_amdgcn_mfma_f32_32x32x16_bf16(k0, qf[s], sa, 0, 0, 0);
      sb = __builtin_amdgcn_mfma_f32_32x32x16_bf16(k1, qf[s], sb, 0, 0, 0);
    }
    __builtin_amdgcn_s_setprio(0);

    // mask (bit o of word = kv offset o within 32-tile); lane's kv = oc + 4h
    const uint32_t mq0 = mmc.x >> (4 * h);
    const uint32_t mq1 = mmc.y >> (4 * h);
#pragma unroll
    for (int r = 0; r < 16; ++r) {
      const int oc = (r & 3) + 8 * (r >> 2);
      if (mq0 & (1u << oc)) sa[r] = -1e30f;
      if (mq1 & (1u << oc)) sb[r] = -1e30f;
    }

    // half-row max (in-lane tree) then cross-half combine
    float x0 = fmaxf(sa[0], sb[0]), x1 = fmaxf(sa[1], sb[1]);
    float x2 = fmaxf(sa[2], sb[2]), x3 = fmaxf(sa[3], sb[3]);
#pragma unroll
    for (int r = 4; r < 16; r += 4) {
      x0 = fmaxf(x0, fmaxf(sa[r], sb[r]));
      x1 = fmaxf(x1, fmaxf(sa[r + 1], sb[r + 1]));
      x2 = fmaxf(x2, fmaxf(sa[r + 2], sb[r + 2]));
      x3 = fmaxf(x3, fmaxf(sa[r + 3], sb[r + 3]));
    }
    float mx = fmaxf(fmaxf(x0, x1), fmaxf(x2, x3)) * K2E;
    mx = row_max2(mx);

    // defer-max rescale (T13); uniform branch. First tile: corr=exp2(-inf)=0
    // also washes out any fully-masked-prefix garbage rows.
    if (!__all(mx <= m_run + 8.f)) {
      float mnew = fmaxf(m_run, mx);
      float corr = exp2a(m_run - mnew);
      l_run *= corr;
#pragma unroll
      for (int r = 0; r < 16; ++r) { Oa[0][r] *= corr; Oa[1][r] *= corr; }
      m_run = mnew;
    }

    // p = 2^(s*K2E - m); masked s=-1e30 -> 0 (once m is real)
    float s0 = 0.f, s1 = 0.f;
#pragma unroll
    for (int r = 0; r < 16; ++r) {
      float e0 = exp2a(fmaf(sa[r], K2E, -m_run));
      float e1 = exp2a(fmaf(sb[r], K2E, -m_run));
      sa[r] = e0; sb[r] = e1;
      s0 += e0; s1 += e1;
    }
    l_run += row_add2(s0 + s1);

    // build P^T B-fragments in-register (T12)
    short8 pf[4];
    pack_frags(sa, pf[0], pf[1]);
    pack_frags(sb, pf[2], pf[3]);

    // O^T += V^T @ P^T
    __builtin_amdgcn_s_setprio(1);
#pragma unroll
    for (int cc = 0; cc < 4; ++cc) {
      short8 v0 = *(const short8*)(vbase + ((cc << 5) ^ hx4));
      short8 v1 = *(const short8*)(vbase + 4096 + ((cc << 5) ^ hx4));
      Oa[0] = __builtin_amdgcn_mfma_f32_32x32x16_bf16(v0, pf[cc], Oa[0], 0, 0, 0);
      Oa[1] = __builtin_amdgcn_mfma_f32_32x32x16_bf16(v1, pf[cc], Oa[1], 0, 0, 0);
    }
    __builtin_amdgcn_s_setprio(0);
    mmc = mmn;
  }

  // epilogue: lane holds col q, rows d = (r&3)+8*(r>>2)+4h+32dt
  float inv = 1.0f / fmaxf(l_run, 1e-30f);
  u16* orow = AO + ((size_t)(b << 11) + q) * 1024 + hd * 64 + h * 4;
#pragma unroll
  for (int dt = 0; dt < 2; ++dt)
#pragma unroll
    for (int rq = 0; rq < 4; ++rq) {
      uint32_t w0 = cvtpk(Oa[dt][4 * rq + 0] * inv, Oa[dt][4 * rq + 1] * inv);
      uint32_t w1 = cvtpk(Oa[dt][4 * rq + 2] * inv, Oa[dt][4 * rq + 3] * inv);
      *(uint32_t*)(orow + dt * 32 + rq * 8) = w0;
      *(uint32_t*)(orow + dt * 32 + rq * 8 + 2) = w1;
    }
#undef STAGE
}

// ---------------- launch ----------------

extern "C" void kernel_launch(void* const* d_in, const int* in_sizes, int n_in,
                              void* d_out, int out_size, void* d_ws, size_t ws_size,
                              hipStream_t stream) {
  const float* x = (const float*)d_in[0];
  const int* mask = (const int*)d_in[1];
  const float* Wqkv = (const float*)d_in[2];
  const float* Wout = (const float*)d_in[3];
  const float* bout = (const float*)d_in[4];
  float* out = (float*)d_out;
  char* ws = (char*)d_ws;
  const size_t MB = 1u << 20;
  if (ws_size < 49 * MB) return;

  u16* xb = (u16*)(ws);                     // 8 MB  [4096][1024]
  u16* wqT = (u16*)(ws + 8 * MB);           // 6 MB  [3072][1024]
  u16* woT = (u16*)(ws + 14 * MB);          // 2 MB  [1024][1024]
  uint32_t* mw = (uint32_t*)(ws + 16 * MB); // 1 MB  [B][2048][64]
  u16* Qb = (u16*)(ws + 17 * MB);           // 8 MB  [B,H,2048,64]
  u16* Kb = (u16*)(ws + 25 * MB);           // 8 MB  [B,H,2048,64]
  u16* VT = (u16*)(ws + 33 * MB);           // 8 MB  [B,H,64,2048]
  u16* AO = (u16*)(ws + 41 * MB);           // 8 MB  [4096][1024]

  k_cvt_x<<<4096, 256, 0, stream>>>(x, xb, 1048576);
  k_transpose_bf<<<dim3(96, 32), dim3(32, 8), 0, stream>>>(Wqkv, wqT, 1024, 3072);
  k_transpose_bf<<<dim3(32, 32), dim3(32, 8), 0, stream>>>(Wout, woT, 1024, 1024);
  k_mask_pack<<<32768, 256, 0, stream>>>(mask, mw, 8388608);
  k_gemm_qkv<<<dim3(24, 32), 256, 0, stream>>>(xb, wqT, Qb, Kb, VT);
  k_attn<<<512, 256, 0, stream>>>(Qb, Kb, VT, mw, AO);
  k_gemm_out<<<dim3(8, 32), 256, 0, stream>>>(AO, woT, bout, out);
}

// Round 3
// 177.504 us; speedup vs baseline: 1.7073x; 1.0907x over previous
//
#include <hip/hip_runtime.h>
#include <stdint.h>

typedef unsigned short u16;
typedef short short8 __attribute__((ext_vector_type(8)));
typedef float f32x4 __attribute__((ext_vector_type(4)));
typedef float f32x16 __attribute__((ext_vector_type(16)));
typedef unsigned int uint2v __attribute__((ext_vector_type(2)));

#define K2E 0.18033688011112042f  /* 0.125 * log2(e) */

__device__ __forceinline__ u16 f2bf(float f) {
  union { float f; uint32_t u; } v;
  v.f = f;
  uint32_t u = v.u;
  u += 0x7FFFu + ((u >> 16) & 1u);
  return (u16)(u >> 16);
}

__device__ __forceinline__ uint32_t cvtpk(float lo, float hi) {
  uint32_t r;
  asm("v_cvt_pk_bf16_f32 %0, %1, %2" : "=v"(r) : "v"(lo), "v"(hi));
  return r;
}

__device__ __forceinline__ float exp2a(float x) {
  float r;
  asm("v_exp_f32 %0, %1" : "=v"(r) : "v"(x));
  return r;
}

// keep-mask: bit `oc` of zm (1=keep) -> 0xFFFFFFFF / 0, and'ed into f32 p
__device__ __forceinline__ float mask_keep(float p, uint32_t zm, int oc) {
  int m = (int)(zm << (31 - oc)) >> 31;   // v_bfe_i32 pattern
  return __uint_as_float(__float_as_uint(p) & (uint32_t)m);
}

__device__ __forceinline__ float row_max2(float x) {
  uint2v r = __builtin_amdgcn_permlane32_swap(__float_as_uint(x), __float_as_uint(x), false, false);
  return fmaxf(__uint_as_float(r.x), __uint_as_float(r.y));
}

__device__ __forceinline__ float row_add2(float x) {
  uint2v r = __builtin_amdgcn_permlane32_swap(__float_as_uint(x), __float_as_uint(x), false, false);
  return __uint_as_float(r.x) + __uint_as_float(r.y);
}

__device__ __forceinline__ void gld_lds16(const u16* src, char* dst) {
  __builtin_amdgcn_global_load_lds((const __attribute__((address_space(1))) void*)src,
                                   (__attribute__((address_space(3))) void*)dst, 16, 0, 0);
}

__device__ __forceinline__ void pack_frags(const f32x16& v, short8& fa, short8& fb) {
  union U { uint32_t w[4]; short8 v8; };
  uint32_t X0 = cvtpk(v[0], v[1]),   X1 = cvtpk(v[2], v[3]);
  uint32_t Y0 = cvtpk(v[4], v[5]),   Y1 = cvtpk(v[6], v[7]);
  uint32_t X2 = cvtpk(v[8], v[9]),   X3 = cvtpk(v[10], v[11]);
  uint32_t Y2 = cvtpk(v[12], v[13]), Y3 = cvtpk(v[14], v[15]);
  uint2v r0 = __builtin_amdgcn_permlane32_swap(X0, Y0, false, false);
  uint2v r1 = __builtin_amdgcn_permlane32_swap(X1, Y1, false, false);
  uint2v r2 = __builtin_amdgcn_permlane32_swap(X2, Y2, false, false);
  uint2v r3 = __builtin_amdgcn_permlane32_swap(X3, Y3, false, false);
  U ua; ua.w[0] = r0.x; ua.w[1] = r1.x; ua.w[2] = r0.y; ua.w[3] = r1.y; fa = ua.v8;
  U ub; ub.w[0] = r2.x; ub.w[1] = r3.x; ub.w[2] = r2.y; ub.w[3] = r3.y; fb = ub.v8;
}

// ---------------- prep kernels ----------------

__global__ __launch_bounds__(256) void k_cvt_x(const float* __restrict__ x,
                                               u16* __restrict__ xb, int n4) {
  int g = blockIdx.x * 256 + threadIdx.x;
  if (g >= n4) return;
  float4 v = ((const float4*)x)[g];
  ushort4 o;
  o.x = f2bf(v.x); o.y = f2bf(v.y); o.z = f2bf(v.z); o.w = f2bf(v.w);
  ((ushort4*)xb)[g] = o;
}

__global__ __launch_bounds__(256) void k_transpose_bf(const float* __restrict__ src,
                                                      u16* __restrict__ dst, int R, int C) {
  __shared__ float t[32][33];
  int c0 = blockIdx.x * 32, r0 = blockIdx.y * 32;
  int tx = threadIdx.x, ty = threadIdx.y;
#pragma unroll
  for (int i = 0; i < 4; ++i)
    t[ty + 8 * i][tx] = src[(size_t)(r0 + ty + 8 * i) * C + c0 + tx];
  __syncthreads();
#pragma unroll
  for (int i = 0; i < 4; ++i)
    dst[(size_t)(c0 + ty + 8 * i) * R + r0 + tx] = f2bf(t[tx][ty + 8 * i]);
}

__global__ __launch_bounds__(256) void k_mask_pack(const int* __restrict__ m,
                                                   uint32_t* __restrict__ w, int n) {
  int g = blockIdx.x * 256 + threadIdx.x;
  if (g >= n) return;
  unsigned long long bal = __ballot(m[g] != 0);
  int lane = threadIdx.x & 63;
  if (lane == 0) w[g >> 5] = (uint32_t)bal;
  else if (lane == 32) w[g >> 5] = (uint32_t)(bal >> 32);
}

// ---------------- GEMM core v2 (m97 structure) ----------------
// 128x128 tile, BK=32, 4 waves 2x2, double-buffered LDS staged via
// global_load_lds w16 with pre-swizzled per-lane global source (rule #21).
// LDS per buffer: A [128][64B] at +0, B at +8192; chunk c of row r holds
// global chunk c ^ ((r>>1)&3); reader applies same XOR.

__device__ __forceinline__ void gemm_core(const u16* __restrict__ A,
                                          const u16* __restrict__ Bt,
                                          int K, int m0, int n0,
                                          f32x4 (&acc)[4][4], char* lds) {
  const int t = threadIdx.x;
  const int l = t & 63;
  const int w = t >> 6;
  const int wm = w >> 1, wn = w & 1;
  const int lr = l & 15, lg = l >> 4;
  const int srow = t >> 2;                       // staging row 0..63 (issue adds 64)
  const int sc = (t & 3) ^ ((srow >> 1) & 3);    // pre-swizzled source chunk
  const u16* As = A + (size_t)(m0 + srow) * K + sc * 8;
  const u16* Bs = Bt + (size_t)(n0 + srow) * K + sc * 8;
  const size_t rstep = (size_t)64 * K;
  const int wbase = w * 1024;                    // wave-uniform LDS offset
  const int nk = K >> 5;

#define GSTAGE(B_, KT_)                                              \
  {                                                                  \
    const u16* a_ = As + ((KT_) << 5);                               \
    const u16* b_ = Bs + ((KT_) << 5);                               \
    char* dA_ = lds + (B_) * 16384 + wbase;                          \
    char* dB_ = dA_ + 8192;                                          \
    gld_lds16(a_, dA_);                                              \
    gld_lds16(a_ + rstep, dA_ + 4096);                               \
    gld_lds16(b_, dB_);                                              \
    gld_lds16(b_ + rstep, dB_ + 4096);                               \
  }

  GSTAGE(0, 0);
#pragma unroll 1
  for (int kt = 0; kt < nk; ++kt) {
    __syncthreads();                      // stage(kt) landed; reads of buf (kt-1) done
    if (kt + 1 < nk) GSTAGE((kt + 1) & 1, kt + 1);
    const char* bA = lds + (kt & 1) * 16384;
    const char* bB = bA + 8192;
    short8 af[4], bfr[4];
#pragma unroll
    for (int mi = 0; mi < 4; ++mi) {
      int row = wm * 64 + mi * 16 + lr;
      af[mi] = *(const short8*)(bA + row * 64 + ((lg ^ ((row >> 1) & 3)) << 4));
    }
#pragma unroll
    for (int ni = 0; ni < 4; ++ni) {
      int row = wn * 64 + ni * 16 + lr;
      bfr[ni] = *(const short8*)(bB + row * 64 + ((lg ^ ((row >> 1) & 3)) << 4));
    }
    __builtin_amdgcn_s_setprio(1);
#pragma unroll
    for (int mi = 0; mi < 4; ++mi)
#pragma unroll
      for (int ni = 0; ni < 4; ++ni)
        acc[mi][ni] = __builtin_amdgcn_mfma_f32_16x16x32_bf16(af[mi], bfr[ni], acc[mi][ni], 0, 0, 0);
    __builtin_amdgcn_s_setprio(0);
  }
#undef GSTAGE
}

__global__ __launch_bounds__(256) void k_gemm_qkv(const u16* __restrict__ xb,
                                                  const u16* __restrict__ wqT,
                                                  u16* __restrict__ Qb,
                                                  u16* __restrict__ Kb,
                                                  u16* __restrict__ VT) {
  __shared__ char lds[32768] __attribute__((aligned(128)));
  int n0 = blockIdx.x * 128, m0 = blockIdx.y * 128;
  f32x4 acc[4][4] = {};
  gemm_core(xb, wqT, 1024, m0, n0, acc, lds);
  const int l = threadIdx.x & 63, w = threadIdx.x >> 6;
  const int wm = w >> 1, wn = w & 1;
  const int lr = l & 15, lg = l >> 4;
#pragma unroll
  for (int mi = 0; mi < 4; ++mi)
#pragma unroll
    for (int ni = 0; ni < 4; ++ni)
#pragma unroll
      for (int r = 0; r < 4; ++r) {
        int m = m0 + wm * 64 + mi * 16 + lg * 4 + r;
        int n = n0 + wn * 64 + ni * 16 + lr;
        int b = m >> 11, seq = m & 2047;
        u16 v = f2bf(acc[mi][ni][r]);
        if (n < 1024) {
          Qb[((size_t)((b << 4) + (n >> 6)) * 2048 + seq) * 64 + (n & 63)] = v;
        } else if (n < 2048) {
          int nn = n - 1024;
          Kb[((size_t)((b << 4) + (nn >> 6)) * 2048 + seq) * 64 + (nn & 63)] = v;
        } else {
          int nn = n - 2048;
          VT[((size_t)((b << 4) + (nn >> 6)) * 64 + (nn & 63)) * 2048 + seq] = v;
        }
      }
}

__global__ __launch_bounds__(256) void k_gemm_out(const u16* __restrict__ ao,
                                                  const u16* __restrict__ woT,
                                                  const float* __restrict__ bias,
                                                  float* __restrict__ out) {
  __shared__ char lds[32768] __attribute__((aligned(128)));
  int n0 = blockIdx.x * 128, m0 = blockIdx.y * 128;
  f32x4 acc[4][4] = {};
  gemm_core(ao, woT, 1024, m0, n0, acc, lds);
  const int l = threadIdx.x & 63, w = threadIdx.x >> 6;
  const int wm = w >> 1, wn = w & 1;
  const int lr = l & 15, lg = l >> 4;
#pragma unroll
  for (int mi = 0; mi < 4; ++mi)
#pragma unroll
    for (int ni = 0; ni < 4; ++ni)
#pragma unroll
      for (int r = 0; r < 4; ++r) {
        int m = m0 + wm * 64 + mi * 16 + lg * 4 + r;
        int n = n0 + wn * 64 + ni * 16 + lr;
        out[(size_t)m * 1024 + n] = acc[mi][ni][r] + bias[n];
      }
}

// ---------------- flash attention v3 ----------------
// As R2 (swapped-QK 32x32, in-register softmax) plus: all K/V frag ds_reads
// hoisted to tile top; mask applied post-exp via sign-bfe AND (max over all
// scores -- inflation only rescales p within f32 range, exact); running
// pointers for staging/mask.
__global__ __launch_bounds__(256) void k_attn(const u16* __restrict__ Qg,
                                              const u16* __restrict__ Kg,
                                              const u16* __restrict__ Vg,
                                              const uint32_t* __restrict__ maskw,
                                              u16* __restrict__ AO) {
  __shared__ char lds[32768] __attribute__((aligned(128)));
  const int bid = blockIdx.x;
  const int qt = bid & 15;
  const int hd = (bid >> 4) & 15;
  const int b = bid >> 8;
  const int bh = (b << 4) + hd;
  const int tx = threadIdx.x, l = tx & 63, w = tx >> 6;
  const int l31 = l & 31, h = l >> 5;
  const int hx4 = (h ^ (l & 7)) << 4;          // read-side swizzle
  const int sc8 = ((l & 7) ^ (l >> 3)) << 3;   // staging source chunk (elems)
  const int lr8 = l >> 3;

  const u16* Qp = Qg + (size_t)bh * 2048 * 64;
  const int q0w = qt * 128 + w * 32;
  const int q = q0w + l31;

  // running staging pointers (per-lane)
  const u16* kg = Kg + (size_t)bh * 2048 * 64 + (size_t)(16 * w + lr8) * 64 + sc8;
  const u16* vg = Vg + (size_t)bh * 64 * 2048 + (size_t)(16 * w + lr8) * 2048 + sc8;
  const uint2v* mp = (const uint2v*)(maskw + ((size_t)(b << 11) + q) * 64);

  short8 qf[4];
#pragma unroll
  for (int s = 0; s < 4; ++s)
    qf[s] = *(const short8*)(Qp + (size_t)q * 64 + s * 16 + h * 8);

  f32x16 Oa[2] = {};
  float m_run = -1e30f, l_run = 0.f;

#define STAGE(BSEL, TT)                                                   \
  {                                                                       \
    char* base_ = lds + (BSEL) * 16384 + 16 * w * 128;                    \
    const u16* k_ = kg + ((size_t)(TT) << 12);                            \
    const u16* v_ = vg + ((size_t)(TT) << 6);                             \
    gld_lds16(k_, base_);                                                 \
    gld_lds16(k_ + 512, base_ + 1024);                                    \
    gld_lds16(v_, base_ + 8192);                                          \
    gld_lds16(v_ + 16384, base_ + 9216);                                  \
  }

  STAGE(0, 0);
  uint2v mmc = mp[0];

#pragma unroll 1
  for (int tt = 0; tt < 32; ++tt) {
    __syncthreads();
    if (tt + 1 < 32) STAGE((tt + 1) & 1, tt + 1);
    uint2v mmn = (tt + 1 < 32) ? mp[tt + 1] : mmc;

    const char* kbase = lds + (tt & 1) * 16384 + l31 * 128;
    const char* vbase = kbase + 8192;

    // hoist ALL fragment reads (V latency hides under QK+softmax)
    short8 kf0[4], kf1[4], vf0[4], vf1[4];
#pragma unroll
    for (int s = 0; s < 4; ++s) {
      kf0[s] = *(const short8*)(kbase + ((s << 5) ^ hx4));
      kf1[s] = *(const short8*)(kbase + 4096 + ((s << 5) ^ hx4));
      vf0[s] = *(const short8*)(vbase + ((s << 5) ^ hx4));
      vf1[s] = *(const short8*)(vbase + 4096 + ((s << 5) ^ hx4));
    }

    f32x16 sa = {}, sb = {};
    __builtin_amdgcn_s_setprio(1);
#pragma unroll
    for (int s = 0; s < 4; ++s) {
      sa = __builtin_amdgcn_mfma_f32_32x32x16_bf16(kf0[s], qf[s], sa, 0, 0, 0);
      sb = __builtin_amdgcn_mfma_f32_32x32x16_bf16(kf1[s], qf[s], sb, 0, 0, 0);
    }
    __builtin_amdgcn_s_setprio(0);

    // max over ALL scores (masked inflation is harmless in f32)
    float x0 = fmaxf(sa[0], sb[0]), x1 = fmaxf(sa[1], sb[1]);
    float x2 = fmaxf(sa[2], sb[2]), x3 = fmaxf(sa[3], sb[3]);
#pragma unroll
    for (int r = 4; r < 16; r += 4) {
      x0 = fmaxf(x0, fmaxf(sa[r], sb[r]));
      x1 = fmaxf(x1, fmaxf(sa[r + 1], sb[r + 1]));
      x2 = fmaxf(x2, fmaxf(sa[r + 2], sb[r + 2]));
      x3 = fmaxf(x3, fmaxf(sa[r + 3], sb[r + 3]));
    }
    float mx = fmaxf(fmaxf(x0, x1), fmaxf(x2, x3)) * K2E;
    mx = row_max2(mx);

    if (!__all(mx <= m_run + 8.f)) {
      float mnew = fmaxf(m_run, mx);
      float corr = exp2a(m_run - mnew);
      l_run *= corr;
#pragma unroll
      for (int r = 0; r < 16; ++r) { Oa[0][r] *= corr; Oa[1][r] *= corr; }
      m_run = mnew;
    }

    // p = 2^(s*K2E - m), then zero masked via sign-bfe AND (2 ops/elem)
    const uint32_t zm0 = ~(mmc.x >> (4 * h));
    const uint32_t zm1 = ~(mmc.y >> (4 * h));
    float s0 = 0.f, s1 = 0.f, s2 = 0.f, s3 = 0.f;
#pragma unroll
    for (int r = 0; r < 16; r += 2) {
      const int oc = (r & 3) + 8 * (r >> 2);
      float e0 = mask_keep(exp2a(fmaf(sa[r], K2E, -m_run)), zm0, oc);
      float e1 = mask_keep(exp2a(fmaf(sb[r], K2E, -m_run)), zm1, oc);
      float e2 = mask_keep(exp2a(fmaf(sa[r + 1], K2E, -m_run)), zm0, oc + 1);
      float e3 = mask_keep(exp2a(fmaf(sb[r + 1], K2E, -m_run)), zm1, oc + 1);
      sa[r] = e0; sb[r] = e1; sa[r + 1] = e2; sb[r + 1] = e3;
      s0 += e0; s1 += e1; s2 += e2; s3 += e3;
    }
    l_run += row_add2((s0 + s2) + (s1 + s3));

    short8 pf[4];
    pack_frags(sa, pf[0], pf[1]);
    pack_frags(sb, pf[2], pf[3]);

    __builtin_amdgcn_s_setprio(1);
#pragma unroll
    for (int cc = 0; cc < 4; ++cc) {
      Oa[0] = __builtin_amdgcn_mfma_f32_32x32x16_bf16(vf0[cc], pf[cc], Oa[0], 0, 0, 0);
      Oa[1] = __builtin_amdgcn_mfma_f32_32x32x16_bf16(vf1[cc], pf[cc], Oa[1], 0, 0, 0);
    }
    __builtin_amdgcn_s_setprio(0);
    mmc = mmn;
  }

  float inv = 1.0f / fmaxf(l_run, 1e-30f);
  u16* orow = AO + ((size_t)(b << 11) + q) * 1024 + hd * 64 + h * 4;
#pragma unroll
  for (int dt = 0; dt < 2; ++dt)
#pragma unroll
    for (int rq = 0; rq < 4; ++rq) {
      uint32_t w0 = cvtpk(Oa[dt][4 * rq + 0] * inv, Oa[dt][4 * rq + 1] * inv);
      uint32_t w1 = cvtpk(Oa[dt][4 * rq + 2] * inv, Oa[dt][4 * rq + 3] * inv);
      *(uint32_t*)(orow + dt * 32 + rq * 8) = w0;
      *(uint32_t*)(orow + dt * 32 + rq * 8 + 2) = w1;
    }
#undef STAGE
}

// ---------------- launch ----------------

extern "C" void kernel_launch(void* const* d_in, const int* in_sizes, int n_in,
                              void* d_out, int out_size, void* d_ws, size_t ws_size,
                              hipStream_t stream) {
  const float* x = (const float*)d_in[0];
  const int* mask = (const int*)d_in[1];
  const float* Wqkv = (const float*)d_in[2];
  const float* Wout = (const float*)d_in[3];
  const float* bout = (const float*)d_in[4];
  float* out = (float*)d_out;
  char* ws = (char*)d_ws;
  const size_t MB = 1u << 20;
  if (ws_size < 49 * MB) return;

  u16* xb = (u16*)(ws);                     // 8 MB  [4096][1024]
  u16* wqT = (u16*)(ws + 8 * MB);           // 6 MB  [3072][1024]
  u16* woT = (u16*)(ws + 14 * MB);          // 2 MB  [1024][1024]
  uint32_t* mw = (uint32_t*)(ws + 16 * MB); // 1 MB  [B][2048][64]
  u16* Qb = (u16*)(ws + 17 * MB);           // 8 MB  [B,H,2048,64]
  u16* Kb = (u16*)(ws + 25 * MB);           // 8 MB  [B,H,2048,64]
  u16* VT = (u16*)(ws + 33 * MB);           // 8 MB  [B,H,64,2048]
  u16* AO = (u16*)(ws + 41 * MB);           // 8 MB  [4096][1024]

  k_cvt_x<<<4096, 256, 0, stream>>>(x, xb, 1048576);
  k_transpose_bf<<<dim3(96, 32), dim3(32, 8), 0, stream>>>(Wqkv, wqT, 1024, 3072);
  k_transpose_bf<<<dim3(32, 32), dim3(32, 8), 0, stream>>>(Wout, woT, 1024, 1024);
  k_mask_pack<<<32768, 256, 0, stream>>>(mask, mw, 8388608);
  k_gemm_qkv<<<dim3(24, 32), 256, 0, stream>>>(xb, wqT, Qb, Kb, VT);
  k_attn<<<512, 256, 0, stream>>>(Qb, Kb, VT, mw, AO);
  k_gemm_out<<<dim3(8, 32), 256, 0, stream>>>(AO, woT, bout, out);
}

// Round 4
// 157.581 us; speedup vs baseline: 1.9232x; 1.1264x over previous
//
#include <hip/hip_runtime.h>
#include <stdint.h>

typedef unsigned short u16;
typedef short short8 __attribute__((ext_vector_type(8)));
typedef float f32x4 __attribute__((ext_vector_type(4)));
typedef float f32x16 __attribute__((ext_vector_type(16)));
typedef unsigned int uint2v __attribute__((ext_vector_type(2)));

#define K2E 0.18033688011112042f  /* 0.125 * log2(e) */

__device__ __forceinline__ u16 f2bf(float f) {
  union { float f; uint32_t u; } v;
  v.f = f;
  uint32_t u = v.u;
  u += 0x7FFFu + ((u >> 16) & 1u);
  return (u16)(u >> 16);
}

__device__ __forceinline__ uint32_t cvtpk(float lo, float hi) {
  uint32_t r;
  asm("v_cvt_pk_bf16_f32 %0, %1, %2" : "=v"(r) : "v"(lo), "v"(hi));
  return r;
}

__device__ __forceinline__ float exp2a(float x) {
  float r;
  asm("v_exp_f32 %0, %1" : "=v"(r) : "v"(x));
  return r;
}

// keep-mask: bit `oc` of zm (1=keep) -> all-ones / 0, AND'ed into f32 p
__device__ __forceinline__ float mask_keep(float p, uint32_t zm, int oc) {
  int m = (int)(zm << (31 - oc)) >> 31;
  return __uint_as_float(__float_as_uint(p) & (uint32_t)m);
}

__device__ __forceinline__ float row_add2(float x) {
  uint2v r = __builtin_amdgcn_permlane32_swap(__float_as_uint(x), __float_as_uint(x), false, false);
  return __uint_as_float(r.x) + __uint_as_float(r.y);
}

__device__ __forceinline__ void gld_lds16(const u16* src, char* dst) {
  __builtin_amdgcn_global_load_lds((const __attribute__((address_space(1))) void*)src,
                                   (__attribute__((address_space(3))) void*)dst, 16, 0, 0);
}

__device__ __forceinline__ void pack_frags(const f32x16& v, short8& fa, short8& fb) {
  union U { uint32_t w[4]; short8 v8; };
  uint32_t X0 = cvtpk(v[0], v[1]),   X1 = cvtpk(v[2], v[3]);
  uint32_t Y0 = cvtpk(v[4], v[5]),   Y1 = cvtpk(v[6], v[7]);
  uint32_t X2 = cvtpk(v[8], v[9]),   X3 = cvtpk(v[10], v[11]);
  uint32_t Y2 = cvtpk(v[12], v[13]), Y3 = cvtpk(v[14], v[15]);
  uint2v r0 = __builtin_amdgcn_permlane32_swap(X0, Y0, false, false);
  uint2v r1 = __builtin_amdgcn_permlane32_swap(X1, Y1, false, false);
  uint2v r2 = __builtin_amdgcn_permlane32_swap(X2, Y2, false, false);
  uint2v r3 = __builtin_amdgcn_permlane32_swap(X3, Y3, false, false);
  U ua; ua.w[0] = r0.x; ua.w[1] = r1.x; ua.w[2] = r0.y; ua.w[3] = r1.y; fa = ua.v8;
  U ub; ub.w[0] = r2.x; ub.w[1] = r3.x; ub.w[2] = r2.y; ub.w[3] = r3.y; fb = ub.v8;
}

// ---------------- prep kernels ----------------

__global__ __launch_bounds__(256) void k_cvt_x(const float* __restrict__ x,
                                               u16* __restrict__ xb, int n4) {
  int g = blockIdx.x * 256 + threadIdx.x;
  if (g >= n4) return;
  float4 v = ((const float4*)x)[g];
  ushort4 o;
  o.x = f2bf(v.x); o.y = f2bf(v.y); o.z = f2bf(v.z); o.w = f2bf(v.w);
  ((ushort4*)xb)[g] = o;
}

__global__ __launch_bounds__(256) void k_transpose_bf(const float* __restrict__ src,
                                                      u16* __restrict__ dst, int R, int C) {
  __shared__ float t[32][33];
  int c0 = blockIdx.x * 32, r0 = blockIdx.y * 32;
  int tx = threadIdx.x, ty = threadIdx.y;
#pragma unroll
  for (int i = 0; i < 4; ++i)
    t[ty + 8 * i][tx] = src[(size_t)(r0 + ty + 8 * i) * C + c0 + tx];
  __syncthreads();
#pragma unroll
  for (int i = 0; i < 4; ++i)
    dst[(size_t)(c0 + ty + 8 * i) * R + r0 + tx] = f2bf(t[tx][ty + 8 * i]);
}

__global__ __launch_bounds__(256) void k_mask_pack(const int* __restrict__ m,
                                                   uint32_t* __restrict__ w, int n) {
  int g = blockIdx.x * 256 + threadIdx.x;
  if (g >= n) return;
  unsigned long long bal = __ballot(m[g] != 0);
  int lane = threadIdx.x & 63;
  if (lane == 0) w[g >> 5] = (uint32_t)bal;
  else if (lane == 32) w[g >> 5] = (uint32_t)(bal >> 32);
}

// ---------------- GEMM core (m97 structure, unchanged from R3) ----------------

__device__ __forceinline__ void gemm_core(const u16* __restrict__ A,
                                          const u16* __restrict__ Bt,
                                          int K, int m0, int n0,
                                          f32x4 (&acc)[4][4], char* lds) {
  const int t = threadIdx.x;
  const int l = t & 63;
  const int w = t >> 6;
  const int wm = w >> 1, wn = w & 1;
  const int lr = l & 15, lg = l >> 4;
  const int srow = t >> 2;
  const int sc = (t & 3) ^ ((srow >> 1) & 3);
  const u16* As = A + (size_t)(m0 + srow) * K + sc * 8;
  const u16* Bs = Bt + (size_t)(n0 + srow) * K + sc * 8;
  const size_t rstep = (size_t)64 * K;
  const int wbase = w * 1024;
  const int nk = K >> 5;

#define GSTAGE(B_, KT_)                                              \
  {                                                                  \
    const u16* a_ = As + ((KT_) << 5);                               \
    const u16* b_ = Bs + ((KT_) << 5);                               \
    char* dA_ = lds + (B_) * 16384 + wbase;                          \
    char* dB_ = dA_ + 8192;                                          \
    gld_lds16(a_, dA_);                                              \
    gld_lds16(a_ + rstep, dA_ + 4096);                               \
    gld_lds16(b_, dB_);                                              \
    gld_lds16(b_ + rstep, dB_ + 4096);                               \
  }

  GSTAGE(0, 0);
#pragma unroll 1
  for (int kt = 0; kt < nk; ++kt) {
    __syncthreads();
    if (kt + 1 < nk) GSTAGE((kt + 1) & 1, kt + 1);
    const char* bA = lds + (kt & 1) * 16384;
    const char* bB = bA + 8192;
    short8 af[4], bfr[4];
#pragma unroll
    for (int mi = 0; mi < 4; ++mi) {
      int row = wm * 64 + mi * 16 + lr;
      af[mi] = *(const short8*)(bA + row * 64 + ((lg ^ ((row >> 1) & 3)) << 4));
    }
#pragma unroll
    for (int ni = 0; ni < 4; ++ni) {
      int row = wn * 64 + ni * 16 + lr;
      bfr[ni] = *(const short8*)(bB + row * 64 + ((lg ^ ((row >> 1) & 3)) << 4));
    }
    __builtin_amdgcn_s_setprio(1);
#pragma unroll
    for (int mi = 0; mi < 4; ++mi)
#pragma unroll
      for (int ni = 0; ni < 4; ++ni)
        acc[mi][ni] = __builtin_amdgcn_mfma_f32_16x16x32_bf16(af[mi], bfr[ni], acc[mi][ni], 0, 0, 0);
    __builtin_amdgcn_s_setprio(0);
  }
#undef GSTAGE
}

__global__ __launch_bounds__(256) void k_gemm_qkv(const u16* __restrict__ xb,
                                                  const u16* __restrict__ wqT,
                                                  u16* __restrict__ Qb,
                                                  u16* __restrict__ Kb,
                                                  u16* __restrict__ VT) {
  __shared__ char lds[32768] __attribute__((aligned(128)));
  int n0 = blockIdx.x * 128, m0 = blockIdx.y * 128;
  f32x4 acc[4][4] = {};
  gemm_core(xb, wqT, 1024, m0, n0, acc, lds);
  const int l = threadIdx.x & 63, w = threadIdx.x >> 6;
  const int wm = w >> 1, wn = w & 1;
  const int lr = l & 15, lg = l >> 4;
#pragma unroll
  for (int mi = 0; mi < 4; ++mi)
#pragma unroll
    for (int ni = 0; ni < 4; ++ni)
#pragma unroll
      for (int r = 0; r < 4; ++r) {
        int m = m0 + wm * 64 + mi * 16 + lg * 4 + r;
        int n = n0 + wn * 64 + ni * 16 + lr;
        int b = m >> 11, seq = m & 2047;
        u16 v = f2bf(acc[mi][ni][r]);
        if (n < 1024) {
          Qb[((size_t)((b << 4) + (n >> 6)) * 2048 + seq) * 64 + (n & 63)] = v;
        } else if (n < 2048) {
          int nn = n - 1024;
          Kb[((size_t)((b << 4) + (nn >> 6)) * 2048 + seq) * 64 + (nn & 63)] = v;
        } else {
          int nn = n - 2048;
          VT[((size_t)((b << 4) + (nn >> 6)) * 64 + (nn & 63)) * 2048 + seq] = v;
        }
      }
}

__global__ __launch_bounds__(256) void k_gemm_out(const u16* __restrict__ ao,
                                                  const u16* __restrict__ woT,
                                                  const float* __restrict__ bias,
                                                  float* __restrict__ out) {
  __shared__ char lds[32768] __attribute__((aligned(128)));
  int n0 = blockIdx.x * 128, m0 = blockIdx.y * 128;
  f32x4 acc[4][4] = {};
  gemm_core(ao, woT, 1024, m0, n0, acc, lds);
  const int l = threadIdx.x & 63, w = threadIdx.x >> 6;
  const int wm = w >> 1, wn = w & 1;
  const int lr = l & 15, lg = l >> 4;
#pragma unroll
  for (int mi = 0; mi < 4; ++mi)
#pragma unroll
    for (int ni = 0; ni < 4; ++ni)
#pragma unroll
      for (int r = 0; r < 4; ++r) {
        int m = m0 + wm * 64 + mi * 16 + lg * 4 + r;
        int n = n0 + wn * 64 + ni * 16 + lr;
        out[(size_t)m * 1024 + n] = acc[mi][ni][r] + bias[n];
      }
}

// ---------------- flash attention v4: kv-split + fixed-max softmax ----------------
// 512 threads = 8 waves = 4 q-subtiles x 2 kv-halves. Each wave: 32 q rows,
// 16 kv-tiles of 64. Fixed-max (scores ~N(0,1), max<6 -> exp in range; softmax
// shift-invariance makes this exact). Merge: O=(O0+O1)/(l0+l1) via LDS.
__global__ __launch_bounds__(512, 4) void k_attn(const u16* __restrict__ Qg,
                                                 const u16* __restrict__ Kg,
                                                 const u16* __restrict__ Vg,
                                                 const uint32_t* __restrict__ maskw,
                                                 u16* __restrict__ AO) {
  __shared__ char lds[65536] __attribute__((aligned(128)));
  const int bid = blockIdx.x;
  const int qt = bid & 15;
  const int hd = (bid >> 4) & 15;
  const int b = bid >> 8;
  const int bh = (b << 4) + hd;
  const int tx = threadIdx.x, l = tx & 63, w = tx >> 6;
  const int wq = w & 3, kvh = w >> 2;
  const int l31 = l & 31, h = l >> 5;
  const int hx4 = (h ^ (l & 7)) << 4;
  const int sc8 = ((l & 7) ^ (l >> 3)) << 3;
  const int lr8 = l >> 3;

  const u16* Qp = Qg + (size_t)bh * 131072;
  const int q = qt * 128 + wq * 32 + l31;
  const int kv0 = kvh << 10;

  const u16* kg = Kg + (size_t)bh * 131072 + (size_t)(kv0 + 16 * wq + lr8) * 64 + sc8;
  const u16* vg = Vg + (size_t)bh * 131072 + (size_t)(16 * wq + lr8) * 2048 + kv0 + sc8;
  const uint2v* mp = (const uint2v*)(maskw + ((size_t)(b << 11) + q) * 64) + (kvh << 4);

  short8 qf[4];
#pragma unroll
  for (int s = 0; s < 4; ++s)
    qf[s] = *(const short8*)(Qp + (size_t)q * 64 + s * 16 + h * 8);

  f32x16 Oa[2] = {};
  float l_run = 0.f;
  char* ldsH = lds + (kvh << 15);

#define STAGE(BSEL, TT)                                       \
  {                                                           \
    char* base_ = ldsH + (BSEL) * 16384 + (wq << 11);         \
    const u16* k_ = kg + ((size_t)(TT) << 12);                \
    const u16* v_ = vg + ((size_t)(TT) << 6);                 \
    gld_lds16(k_, base_);                                     \
    gld_lds16(k_ + 512, base_ + 1024);                        \
    gld_lds16(v_, base_ + 8192);                              \
    gld_lds16(v_ + 16384, base_ + 9216);                      \
  }

  STAGE(0, 0);

#pragma unroll 1
  for (int tt = 0; tt < 16; ++tt) {
    __syncthreads();
    if (tt + 1 < 16) STAGE((tt + 1) & 1, tt + 1);
    const uint2v mm = mp[tt];
    const char* kbase = ldsH + (tt & 1) * 16384 + l31 * 128;
    const char* vbase = kbase + 8192;

    f32x16 sa = {}, sb = {};
    __builtin_amdgcn_s_setprio(1);
#pragma unroll
    for (int s = 0; s < 4; ++s) {
      short8 k0 = *(const short8*)(kbase + ((s << 5) ^ hx4));
      short8 k1 = *(const short8*)(kbase + 4096 + ((s << 5) ^ hx4));
      sa = __builtin_amdgcn_mfma_f32_32x32x16_bf16(k0, qf[s], sa, 0, 0, 0);
      sb = __builtin_amdgcn_mfma_f32_32x32x16_bf16(k1, qf[s], sb, 0, 0, 0);
    }
    __builtin_amdgcn_s_setprio(0);

    // p = 2^(s*K2E), mask via sign-bfe AND (fixed-max: no max tracking)
    const uint32_t zm0 = ~(mm.x >> (4 * h));
    const uint32_t zm1 = ~(mm.y >> (4 * h));
    float s0 = 0.f, s1 = 0.f, s2 = 0.f, s3 = 0.f;
#pragma unroll
    for (int r = 0; r < 16; r += 2) {
      const int oc = (r & 3) + 8 * (r >> 2);
      float e0 = mask_keep(exp2a(sa[r] * K2E), zm0, oc);
      float e1 = mask_keep(exp2a(sb[r] * K2E), zm1, oc);
      float e2 = mask_keep(exp2a(sa[r + 1] * K2E), zm0, oc + 1);
      float e3 = mask_keep(exp2a(sb[r + 1] * K2E), zm1, oc + 1);
      sa[r] = e0; sb[r] = e1; sa[r + 1] = e2; sb[r + 1] = e3;
      s0 += e0; s1 += e1; s2 += e2; s3 += e3;
    }
    l_run += row_add2((s0 + s2) + (s1 + s3));

    short8 pf[4];
    pack_frags(sa, pf[0], pf[1]);
    pack_frags(sb, pf[2], pf[3]);

    __builtin_amdgcn_s_setprio(1);
#pragma unroll
    for (int cc = 0; cc < 4; ++cc) {
      short8 v0 = *(const short8*)(vbase + ((cc << 5) ^ hx4));
      short8 v1 = *(const short8*)(vbase + 4096 + ((cc << 5) ^ hx4));
      Oa[0] = __builtin_amdgcn_mfma_f32_32x32x16_bf16(v0, pf[cc], Oa[0], 0, 0, 0);
      Oa[1] = __builtin_amdgcn_mfma_f32_32x32x16_bf16(v1, pf[cc], Oa[1], 0, 0, 0);
    }
    __builtin_amdgcn_s_setprio(0);
  }
#undef STAGE

  // ---- merge kv-halves: O = (O0+O1)/(l0+l1) ----
  __syncthreads();
  float* cb = (float*)lds;
  if (kvh) {
#pragma unroll
    for (int r = 0; r < 32; ++r)
      cb[((wq << 5) + r) * 64 + l] = Oa[r >> 4][r & 15];
    cb[8192 + (wq << 6) + l] = l_run;
  }
  __syncthreads();
  if (!kvh) {
#pragma unroll
    for (int r = 0; r < 32; ++r)
      Oa[r >> 4][r & 15] += cb[((wq << 5) + r) * 64 + l];
    float lt = l_run + cb[8192 + (wq << 6) + l];
    float inv = 1.0f / fmaxf(lt, 1e-30f);
    u16* orow = AO + ((size_t)(b << 11) + q) * 1024 + hd * 64 + h * 4;
#pragma unroll
    for (int dt = 0; dt < 2; ++dt)
#pragma unroll
      for (int rq = 0; rq < 4; ++rq) {
        uint32_t w0 = cvtpk(Oa[dt][4 * rq + 0] * inv, Oa[dt][4 * rq + 1] * inv);
        uint32_t w1 = cvtpk(Oa[dt][4 * rq + 2] * inv, Oa[dt][4 * rq + 3] * inv);
        *(uint32_t*)(orow + dt * 32 + rq * 8) = w0;
        *(uint32_t*)(orow + dt * 32 + rq * 8 + 2) = w1;
      }
  }
}

// ---------------- launch ----------------

extern "C" void kernel_launch(void* const* d_in, const int* in_sizes, int n_in,
                              void* d_out, int out_size, void* d_ws, size_t ws_size,
                              hipStream_t stream) {
  const float* x = (const float*)d_in[0];
  const int* mask = (const int*)d_in[1];
  const float* Wqkv = (const float*)d_in[2];
  const float* Wout = (const float*)d_in[3];
  const float* bout = (const float*)d_in[4];
  float* out = (float*)d_out;
  char* ws = (char*)d_ws;
  const size_t MB = 1u << 20;
  if (ws_size < 49 * MB) return;

  u16* xb = (u16*)(ws);                     // 8 MB  [4096][1024]
  u16* wqT = (u16*)(ws + 8 * MB);           // 6 MB  [3072][1024]
  u16* woT = (u16*)(ws + 14 * MB);          // 2 MB  [1024][1024]
  uint32_t* mw = (uint32_t*)(ws + 16 * MB); // 1 MB  [B][2048][64]
  u16* Qb = (u16*)(ws + 17 * MB);           // 8 MB  [B,H,2048,64]
  u16* Kb = (u16*)(ws + 25 * MB);           // 8 MB  [B,H,2048,64]
  u16* VT = (u16*)(ws + 33 * MB);           // 8 MB  [B,H,64,2048]
  u16* AO = (u16*)(ws + 41 * MB);           // 8 MB  [4096][1024]

  k_cvt_x<<<4096, 256, 0, stream>>>(x, xb, 1048576);
  k_transpose_bf<<<dim3(96, 32), dim3(32, 8), 0, stream>>>(Wqkv, wqT, 1024, 3072);
  k_transpose_bf<<<dim3(32, 32), dim3(32, 8), 0, stream>>>(Wout, woT, 1024, 1024);
  k_mask_pack<<<32768, 256, 0, stream>>>(mask, mw, 8388608);
  k_gemm_qkv<<<dim3(24, 32), 256, 0, stream>>>(xb, wqT, Qb, Kb, VT);
  k_attn<<<512, 512, 0, stream>>>(Qb, Kb, VT, mw, AO);
  k_gemm_out<<<dim3(8, 32), 256, 0, stream>>>(AO, woT, bout, out);
}

// Round 5
// 150.607 us; speedup vs baseline: 2.0122x; 1.0463x over previous
//
#include <hip/hip_runtime.h>
#include <stdint.h>

typedef unsigned short u16;
typedef short short8 __attribute__((ext_vector_type(8)));
typedef float f32x4 __attribute__((ext_vector_type(4)));
typedef float f32x16 __attribute__((ext_vector_type(16)));
typedef unsigned int uint2v __attribute__((ext_vector_type(2)));

#define K2E 0.18033688011112042f  /* 0.125 * log2(e) */

__device__ __forceinline__ u16 f2bf(float f) {
  union { float f; uint32_t u; } v;
  v.f = f;
  uint32_t u = v.u;
  u += 0x7FFFu + ((u >> 16) & 1u);
  return (u16)(u >> 16);
}

__device__ __forceinline__ uint32_t cvtpk(float lo, float hi) {
  uint32_t r;
  asm("v_cvt_pk_bf16_f32 %0, %1, %2" : "=v"(r) : "v"(lo), "v"(hi));
  return r;
}

__device__ __forceinline__ float exp2a(float x) {
  float r;
  asm("v_exp_f32 %0, %1" : "=v"(r) : "v"(x));
  return r;
}

__device__ __forceinline__ float mask_keep(float p, uint32_t zm, int oc) {
  int m = (int)(zm << (31 - oc)) >> 31;
  return __uint_as_float(__float_as_uint(p) & (uint32_t)m);
}

__device__ __forceinline__ float row_add2(float x) {
  uint2v r = __builtin_amdgcn_permlane32_swap(__float_as_uint(x), __float_as_uint(x), false, false);
  return __uint_as_float(r.x) + __uint_as_float(r.y);
}

__device__ __forceinline__ void gld_lds16(const u16* src, char* dst) {
  __builtin_amdgcn_global_load_lds((const __attribute__((address_space(1))) void*)src,
                                   (__attribute__((address_space(3))) void*)dst, 16, 0, 0);
}

__device__ __forceinline__ void pack_frags(const f32x16& v, short8& fa, short8& fb) {
  union U { uint32_t w[4]; short8 v8; };
  uint32_t X0 = cvtpk(v[0], v[1]),   X1 = cvtpk(v[2], v[3]);
  uint32_t Y0 = cvtpk(v[4], v[5]),   Y1 = cvtpk(v[6], v[7]);
  uint32_t X2 = cvtpk(v[8], v[9]),   X3 = cvtpk(v[10], v[11]);
  uint32_t Y2 = cvtpk(v[12], v[13]), Y3 = cvtpk(v[14], v[15]);
  uint2v r0 = __builtin_amdgcn_permlane32_swap(X0, Y0, false, false);
  uint2v r1 = __builtin_amdgcn_permlane32_swap(X1, Y1, false, false);
  uint2v r2 = __builtin_amdgcn_permlane32_swap(X2, Y2, false, false);
  uint2v r3 = __builtin_amdgcn_permlane32_swap(X3, Y3, false, false);
  U ua; ua.w[0] = r0.x; ua.w[1] = r1.x; ua.w[2] = r0.y; ua.w[3] = r1.y; fa = ua.v8;
  U ub; ub.w[0] = r2.x; ub.w[1] = r3.x; ub.w[2] = r2.y; ub.w[3] = r3.y; fb = ub.v8;
}

// ---------------- prep kernels ----------------

__global__ __launch_bounds__(256) void k_cvt_x(const float* __restrict__ x,
                                               u16* __restrict__ xb, int n4) {
  int g = blockIdx.x * 256 + threadIdx.x;
  if (g >= n4) return;
  float4 v = ((const float4*)x)[g];
  ushort4 o;
  o.x = f2bf(v.x); o.y = f2bf(v.y); o.z = f2bf(v.z); o.w = f2bf(v.w);
  ((ushort4*)xb)[g] = o;
}

__global__ __launch_bounds__(256) void k_transpose_bf(const float* __restrict__ src,
                                                      u16* __restrict__ dst, int R, int C) {
  __shared__ float t[32][33];
  int c0 = blockIdx.x * 32, r0 = blockIdx.y * 32;
  int tx = threadIdx.x, ty = threadIdx.y;
#pragma unroll
  for (int i = 0; i < 4; ++i)
    t[ty + 8 * i][tx] = src[(size_t)(r0 + ty + 8 * i) * C + c0 + tx];
  __syncthreads();
#pragma unroll
  for (int i = 0; i < 4; ++i)
    dst[(size_t)(c0 + ty + 8 * i) * R + r0 + tx] = f2bf(t[tx][ty + 8 * i]);
}

__global__ __launch_bounds__(256) void k_mask_pack(const int* __restrict__ m,
                                                   uint32_t* __restrict__ w, int n) {
  int g = blockIdx.x * 256 + threadIdx.x;
  if (g >= n) return;
  unsigned long long bal = __ballot(m[g] != 0);
  int lane = threadIdx.x & 63;
  if (lane == 0) w[g >> 5] = (uint32_t)bal;
  else if (lane == 32) w[g >> 5] = (uint32_t)(bal >> 32);
}

// ---------------- GEMM core v3: phase-split + counted vmcnt (T3+T4) ----------------
// 128x128 tile, 4 waves 2x2, BK=64 as 2 half-K phases of 32. LDS = 2 dbuf x
// 2 half x (A 8KB + B 8KB) = 64 KB. Unit (kt,h) staged at phase(kt-2,h) ->
// prefetch distance 4 phases (~>1000 cyc) covers HBM latency. vmcnt(12) =
// 3 in-flight units x 4 loads (T4 formula); main loop never drains to 0.
// Safety: region restaged == region just consumed; stage issue happens after
// [all waves lgkmcnt(0)'d their reads -> barrier]. Consumption guarded by
// per-wave vmcnt + barrier. Raw s_barrier (no compiler drain) throughout.

#define GSTAGE(BUF, H, KT2)                                              \
  {                                                                      \
    char* dA_ = lds + (BUF) * 32768 + (H) * 16384 + (w << 11);           \
    const u16* a_ = As + (((KT2) << 6) + ((H) << 5));                    \
    const u16* b_ = Bs + (((KT2) << 6) + ((H) << 5));                    \
    gld_lds16(a_, dA_);                                                  \
    gld_lds16(a_ + (K << 4), dA_ + 1024);                                \
    gld_lds16(b_, dA_ + 8192);                                           \
    gld_lds16(b_ + (K << 4), dA_ + 9216);                                \
  }

#define PHASE(KT, H, VMS, DOSTAGE)                                                        \
  {                                                                                       \
    asm volatile("s_waitcnt vmcnt(" VMS ")" ::: "memory");                                \
    __builtin_amdgcn_sched_barrier(0);                                                    \
    __builtin_amdgcn_s_barrier();                                                         \
    __builtin_amdgcn_sched_barrier(0);                                                    \
    const char* rb_ = lds + ((KT) & 1) * 32768 + (H) * 16384;                             \
    short8 af[4], bfr[4];                                                                 \
    _Pragma("unroll")                                                                     \
    for (int mi = 0; mi < 4; ++mi) {                                                      \
      int row = wm * 64 + mi * 16 + lr;                                                   \
      af[mi] = *(const short8*)(rb_ + row * 64 + ((lg ^ ((row >> 1) & 3)) << 4));         \
    }                                                                                     \
    _Pragma("unroll")                                                                     \
    for (int ni = 0; ni < 4; ++ni) {                                                      \
      int row = wn * 64 + ni * 16 + lr;                                                   \
      bfr[ni] = *(const short8*)(rb_ + 8192 + row * 64 + ((lg ^ ((row >> 1) & 3)) << 4)); \
    }                                                                                     \
    asm volatile("s_waitcnt lgkmcnt(0)" ::: "memory");                                    \
    __builtin_amdgcn_sched_barrier(0);                                                    \
    __builtin_amdgcn_s_barrier();                                                         \
    __builtin_amdgcn_sched_barrier(0);                                                    \
    if (DOSTAGE) GSTAGE((KT) & 1, H, (KT) + 2);                                           \
    __builtin_amdgcn_s_setprio(1);                                                        \
    _Pragma("unroll")                                                                     \
    for (int mi = 0; mi < 4; ++mi)                                                        \
      _Pragma("unroll")                                                                   \
      for (int ni = 0; ni < 4; ++ni)                                                      \
        acc[mi][ni] =                                                                     \
            __builtin_amdgcn_mfma_f32_16x16x32_bf16(af[mi], bfr[ni], acc[mi][ni], 0, 0, 0); \
    __builtin_amdgcn_s_setprio(0);                                                        \
  }

__device__ __forceinline__ void gemm_core(const u16* __restrict__ A,
                                          const u16* __restrict__ Bt,
                                          int K, int m0, int n0,
                                          f32x4 (&acc)[4][4], char* lds) {
  const int t = threadIdx.x;
  const int l = t & 63;
  const int w = t >> 6;
  const int wm = w >> 1, wn = w & 1;
  const int lr = l & 15, lg = l >> 4;
  // staging per-lane source: row r0 = w*32 + (l>>2), chunk c = (l&3)^((r0>>1)&3)
  const int r0 = (w << 5) + (l >> 2);
  const int c = (l & 3) ^ ((r0 >> 1) & 3);
  const u16* As = A + (size_t)(m0 + r0) * K + c * 8;
  const u16* Bs = Bt + (size_t)(n0 + r0) * K + c * 8;
  const int nkt = K >> 6;  // 16 for K=1024

  GSTAGE(0, 0, 0);
  GSTAGE(0, 1, 0);
  GSTAGE(1, 0, 1);
  GSTAGE(1, 1, 1);

#pragma unroll 1
  for (int kt = 0; kt < nkt - 2; ++kt) {
    PHASE(kt, 0, "12", true);
    PHASE(kt, 1, "12", true);
  }
  PHASE(nkt - 2, 0, "12", false);
  PHASE(nkt - 2, 1, "8", false);
  PHASE(nkt - 1, 0, "4", false);
  PHASE(nkt - 1, 1, "0", false);
}

__global__ __launch_bounds__(256, 2) void k_gemm_qkv(const u16* __restrict__ xb,
                                                     const u16* __restrict__ wqT,
                                                     u16* __restrict__ Qb,
                                                     u16* __restrict__ Kb,
                                                     u16* __restrict__ VT) {
  __shared__ char lds[65536] __attribute__((aligned(128)));
  int n0 = blockIdx.x * 128, m0 = blockIdx.y * 128;
  f32x4 acc[4][4] = {};
  gemm_core(xb, wqT, 1024, m0, n0, acc, lds);
  const int l = threadIdx.x & 63, w = threadIdx.x >> 6;
  const int wm = w >> 1, wn = w & 1;
  const int lr = l & 15, lg = l >> 4;
#pragma unroll
  for (int mi = 0; mi < 4; ++mi)
#pragma unroll
    for (int ni = 0; ni < 4; ++ni)
#pragma unroll
      for (int r = 0; r < 4; ++r) {
        int m = m0 + wm * 64 + mi * 16 + lg * 4 + r;
        int n = n0 + wn * 64 + ni * 16 + lr;
        int b = m >> 11, seq = m & 2047;
        u16 v = f2bf(acc[mi][ni][r]);
        if (n < 1024) {
          Qb[((size_t)((b << 4) + (n >> 6)) * 2048 + seq) * 64 + (n & 63)] = v;
        } else if (n < 2048) {
          int nn = n - 1024;
          Kb[((size_t)((b << 4) + (nn >> 6)) * 2048 + seq) * 64 + (nn & 63)] = v;
        } else {
          int nn = n - 2048;
          VT[((size_t)((b << 4) + (nn >> 6)) * 64 + (nn & 63)) * 2048 + seq] = v;
        }
      }
}

__global__ __launch_bounds__(256, 2) void k_gemm_out(const u16* __restrict__ ao,
                                                     const u16* __restrict__ woT,
                                                     const float* __restrict__ bias,
                                                     float* __restrict__ out) {
  __shared__ char lds[65536] __attribute__((aligned(128)));
  int n0 = blockIdx.x * 128, m0 = blockIdx.y * 128;
  f32x4 acc[4][4] = {};
  gemm_core(ao, woT, 1024, m0, n0, acc, lds);
  const int l = threadIdx.x & 63, w = threadIdx.x >> 6;
  const int wm = w >> 1, wn = w & 1;
  const int lr = l & 15, lg = l >> 4;
#pragma unroll
  for (int mi = 0; mi < 4; ++mi)
#pragma unroll
    for (int ni = 0; ni < 4; ++ni)
#pragma unroll
      for (int r = 0; r < 4; ++r) {
        int m = m0 + wm * 64 + mi * 16 + lg * 4 + r;
        int n = n0 + wn * 64 + ni * 16 + lr;
        out[(size_t)m * 1024 + n] = acc[mi][ni][r] + bias[n];
      }
}

// ---------------- flash attention v4 (unchanged from R4) ----------------
__global__ __launch_bounds__(512, 4) void k_attn(const u16* __restrict__ Qg,
                                                 const u16* __restrict__ Kg,
                                                 const u16* __restrict__ Vg,
                                                 const uint32_t* __restrict__ maskw,
                                                 u16* __restrict__ AO) {
  __shared__ char lds[65536] __attribute__((aligned(128)));
  const int bid = blockIdx.x;
  const int qt = bid & 15;
  const int hd = (bid >> 4) & 15;
  const int b = bid >> 8;
  const int bh = (b << 4) + hd;
  const int tx = threadIdx.x, l = tx & 63, w = tx >> 6;
  const int wq = w & 3, kvh = w >> 2;
  const int l31 = l & 31, h = l >> 5;
  const int hx4 = (h ^ (l & 7)) << 4;
  const int sc8 = ((l & 7) ^ (l >> 3)) << 3;
  const int lr8 = l >> 3;

  const u16* Qp = Qg + (size_t)bh * 131072;
  const int q = qt * 128 + wq * 32 + l31;
  const int kv0 = kvh << 10;

  const u16* kg = Kg + (size_t)bh * 131072 + (size_t)(kv0 + 16 * wq + lr8) * 64 + sc8;
  const u16* vg = Vg + (size_t)bh * 131072 + (size_t)(16 * wq + lr8) * 2048 + kv0 + sc8;
  const uint2v* mp = (const uint2v*)(maskw + ((size_t)(b << 11) + q) * 64) + (kvh << 4);

  short8 qf[4];
#pragma unroll
  for (int s = 0; s < 4; ++s)
    qf[s] = *(const short8*)(Qp + (size_t)q * 64 + s * 16 + h * 8);

  f32x16 Oa[2] = {};
  float l_run = 0.f;
  char* ldsH = lds + (kvh << 15);

#define STAGE(BSEL, TT)                                       \
  {                                                           \
    char* base_ = ldsH + (BSEL) * 16384 + (wq << 11);         \
    const u16* k_ = kg + ((size_t)(TT) << 12);                \
    const u16* v_ = vg + ((size_t)(TT) << 6);                 \
    gld_lds16(k_, base_);                                     \
    gld_lds16(k_ + 512, base_ + 1024);                        \
    gld_lds16(v_, base_ + 8192);                              \
    gld_lds16(v_ + 16384, base_ + 9216);                      \
  }

  STAGE(0, 0);

#pragma unroll 1
  for (int tt = 0; tt < 16; ++tt) {
    __syncthreads();
    if (tt + 1 < 16) STAGE((tt + 1) & 1, tt + 1);
    const uint2v mm = mp[tt];
    const char* kbase = ldsH + (tt & 1) * 16384 + l31 * 128;
    const char* vbase = kbase + 8192;

    f32x16 sa = {}, sb = {};
    __builtin_amdgcn_s_setprio(1);
#pragma unroll
    for (int s = 0; s < 4; ++s) {
      short8 k0 = *(const short8*)(kbase + ((s << 5) ^ hx4));
      short8 k1 = *(const short8*)(kbase + 4096 + ((s << 5) ^ hx4));
      sa = __builtin_amdgcn_mfma_f32_32x32x16_bf16(k0, qf[s], sa, 0, 0, 0);
      sb = __builtin_amdgcn_mfma_f32_32x32x16_bf16(k1, qf[s], sb, 0, 0, 0);
    }
    __builtin_amdgcn_s_setprio(0);

    const uint32_t zm0 = ~(mm.x >> (4 * h));
    const uint32_t zm1 = ~(mm.y >> (4 * h));
    float s0 = 0.f, s1 = 0.f, s2 = 0.f, s3 = 0.f;
#pragma unroll
    for (int r = 0; r < 16; r += 2) {
      const int oc = (r & 3) + 8 * (r >> 2);
      float e0 = mask_keep(exp2a(sa[r] * K2E), zm0, oc);
      float e1 = mask_keep(exp2a(sb[r] * K2E), zm1, oc);
      float e2 = mask_keep(exp2a(sa[r + 1] * K2E), zm0, oc + 1);
      float e3 = mask_keep(exp2a(sb[r + 1] * K2E), zm1, oc + 1);
      sa[r] = e0; sb[r] = e1; sa[r + 1] = e2; sb[r + 1] = e3;
      s0 += e0; s1 += e1; s2 += e2; s3 += e3;
    }
    l_run += row_add2((s0 + s2) + (s1 + s3));

    short8 pf[4];
    pack_frags(sa, pf[0], pf[1]);
    pack_frags(sb, pf[2], pf[3]);

    __builtin_amdgcn_s_setprio(1);
#pragma unroll
    for (int cc = 0; cc < 4; ++cc) {
      short8 v0 = *(const short8*)(vbase + ((cc << 5) ^ hx4));
      short8 v1 = *(const short8*)(vbase + 4096 + ((cc << 5) ^ hx4));
      Oa[0] = __builtin_amdgcn_mfma_f32_32x32x16_bf16(v0, pf[cc], Oa[0], 0, 0, 0);
      Oa[1] = __builtin_amdgcn_mfma_f32_32x32x16_bf16(v1, pf[cc], Oa[1], 0, 0, 0);
    }
    __builtin_amdgcn_s_setprio(0);
  }
#undef STAGE

  __syncthreads();
  float* cb = (float*)lds;
  if (kvh) {
#pragma unroll
    for (int r = 0; r < 32; ++r)
      cb[((wq << 5) + r) * 64 + l] = Oa[r >> 4][r & 15];
    cb[8192 + (wq << 6) + l] = l_run;
  }
  __syncthreads();
  if (!kvh) {
#pragma unroll
    for (int r = 0; r < 32; ++r)
      Oa[r >> 4][r & 15] += cb[((wq << 5) + r) * 64 + l];
    float lt = l_run + cb[8192 + (wq << 6) + l];
    float inv = 1.0f / fmaxf(lt, 1e-30f);
    u16* orow = AO + ((size_t)(b << 11) + q) * 1024 + hd * 64 + h * 4;
#pragma unroll
    for (int dt = 0; dt < 2; ++dt)
#pragma unroll
      for (int rq = 0; rq < 4; ++rq) {
        uint32_t w0 = cvtpk(Oa[dt][4 * rq + 0] * inv, Oa[dt][4 * rq + 1] * inv);
        uint32_t w1 = cvtpk(Oa[dt][4 * rq + 2] * inv, Oa[dt][4 * rq + 3] * inv);
        *(uint32_t*)(orow + dt * 32 + rq * 8) = w0;
        *(uint32_t*)(orow + dt * 32 + rq * 8 + 2) = w1;
      }
  }
}

// ---------------- launch ----------------

extern "C" void kernel_launch(void* const* d_in, const int* in_sizes, int n_in,
                              void* d_out, int out_size, void* d_ws, size_t ws_size,
                              hipStream_t stream) {
  const float* x = (const float*)d_in[0];
  const int* mask = (const int*)d_in[1];
  const float* Wqkv = (const float*)d_in[2];
  const float* Wout = (const float*)d_in[3];
  const float* bout = (const float*)d_in[4];
  float* out = (float*)d_out;
  char* ws = (char*)d_ws;
  const size_t MB = 1u << 20;
  if (ws_size < 49 * MB) return;

  u16* xb = (u16*)(ws);                     // 8 MB  [4096][1024]
  u16* wqT = (u16*)(ws + 8 * MB);           // 6 MB  [3072][1024]
  u16* woT = (u16*)(ws + 14 * MB);          // 2 MB  [1024][1024]
  uint32_t* mw = (uint32_t*)(ws + 16 * MB); // 1 MB  [B][2048][64]
  u16* Qb = (u16*)(ws + 17 * MB);           // 8 MB  [B,H,2048,64]
  u16* Kb = (u16*)(ws + 25 * MB);           // 8 MB  [B,H,2048,64]
  u16* VT = (u16*)(ws + 33 * MB);           // 8 MB  [B,H,64,2048]
  u16* AO = (u16*)(ws + 41 * MB);           // 8 MB  [4096][1024]

  k_cvt_x<<<4096, 256, 0, stream>>>(x, xb, 1048576);
  k_transpose_bf<<<dim3(96, 32), dim3(32, 8), 0, stream>>>(Wqkv, wqT, 1024, 3072);
  k_transpose_bf<<<dim3(32, 32), dim3(32, 8), 0, stream>>>(Wout, woT, 1024, 1024);
  k_mask_pack<<<32768, 256, 0, stream>>>(mask, mw, 8388608);
  k_gemm_qkv<<<dim3(24, 32), 256, 0, stream>>>(xb, wqT, Qb, Kb, VT);
  k_attn<<<512, 512, 0, stream>>>(Qb, Kb, VT, mw, AO);
  k_gemm_out<<<dim3(8, 32), 256, 0, stream>>>(AO, woT, bout, out);
}

// Round 6
// 136.507 us; speedup vs baseline: 2.2201x; 1.1033x over previous
//
#include <hip/hip_runtime.h>
#include <stdint.h>

typedef unsigned short u16;
typedef short short8 __attribute__((ext_vector_type(8)));
typedef float f32x4 __attribute__((ext_vector_type(4)));
typedef float f32x16 __attribute__((ext_vector_type(16)));
typedef unsigned int uint2v __attribute__((ext_vector_type(2)));

#define K2E 0.18033688011112042f  /* 0.125 * log2(e) */

__device__ __forceinline__ u16 f2bf(float f) {
  union { float f; uint32_t u; } v;
  v.f = f;
  uint32_t u = v.u;
  u += 0x7FFFu + ((u >> 16) & 1u);
  return (u16)(u >> 16);
}

__device__ __forceinline__ uint32_t cvtpk(float lo, float hi) {
  uint32_t r;
  asm("v_cvt_pk_bf16_f32 %0, %1, %2" : "=v"(r) : "v"(lo), "v"(hi));
  return r;
}

__device__ __forceinline__ float exp2a(float x) {
  float r;
  asm("v_exp_f32 %0, %1" : "=v"(r) : "v"(x));
  return r;
}

// zero p where bit oc of zm == 1 (masked): sbfe (1 op) + bfi (1 op)
__device__ __forceinline__ float mask_zero(float p, uint32_t zm, int oc) {
  int mext = __builtin_amdgcn_sbfe((int)zm, oc, 1);  // all-ones if masked
  float r;
  asm("v_bfi_b32 %0, %1, 0, %2" : "=v"(r) : "v"(mext), "v"(p));
  return r;
}

__device__ __forceinline__ void gld_lds16(const u16* src, char* dst) {
  __builtin_amdgcn_global_load_lds((const __attribute__((address_space(1))) void*)src,
                                   (__attribute__((address_space(3))) void*)dst, 16, 0, 0);
}

__device__ __forceinline__ void pack_frags(const f32x16& v, short8& fa, short8& fb) {
  union U { uint32_t w[4]; short8 v8; };
  uint32_t X0 = cvtpk(v[0], v[1]),   X1 = cvtpk(v[2], v[3]);
  uint32_t Y0 = cvtpk(v[4], v[5]),   Y1 = cvtpk(v[6], v[7]);
  uint32_t X2 = cvtpk(v[8], v[9]),   X3 = cvtpk(v[10], v[11]);
  uint32_t Y2 = cvtpk(v[12], v[13]), Y3 = cvtpk(v[14], v[15]);
  uint2v r0 = __builtin_amdgcn_permlane32_swap(X0, Y0, false, false);
  uint2v r1 = __builtin_amdgcn_permlane32_swap(X1, Y1, false, false);
  uint2v r2 = __builtin_amdgcn_permlane32_swap(X2, Y2, false, false);
  uint2v r3 = __builtin_amdgcn_permlane32_swap(X3, Y3, false, false);
  U ua; ua.w[0] = r0.x; ua.w[1] = r1.x; ua.w[2] = r0.y; ua.w[3] = r1.y; fa = ua.v8;
  U ub; ub.w[0] = r2.x; ub.w[1] = r3.x; ub.w[2] = r2.y; ub.w[3] = r3.y; fb = ub.v8;
}

// ---------------- prep kernels ----------------

__global__ __launch_bounds__(256) void k_cvt_x(const float* __restrict__ x,
                                               u16* __restrict__ xb, int n4) {
  int g = blockIdx.x * 256 + threadIdx.x;
  if (g >= n4) return;
  float4 v = ((const float4*)x)[g];
  ushort4 o;
  o.x = f2bf(v.x); o.y = f2bf(v.y); o.z = f2bf(v.z); o.w = f2bf(v.w);
  ((ushort4*)xb)[g] = o;
}

__global__ __launch_bounds__(256) void k_transpose_bf(const float* __restrict__ src,
                                                      u16* __restrict__ dst, int R, int C) {
  __shared__ float t[32][33];
  int c0 = blockIdx.x * 32, r0 = blockIdx.y * 32;
  int tx = threadIdx.x, ty = threadIdx.y;
#pragma unroll
  for (int i = 0; i < 4; ++i)
    t[ty + 8 * i][tx] = src[(size_t)(r0 + ty + 8 * i) * C + c0 + tx];
  __syncthreads();
#pragma unroll
  for (int i = 0; i < 4; ++i)
    dst[(size_t)(c0 + ty + 8 * i) * R + r0 + tx] = f2bf(t[tx][ty + 8 * i]);
}

__global__ __launch_bounds__(256) void k_mask_pack(const int* __restrict__ m,
                                                   uint32_t* __restrict__ w, int n) {
  int g = blockIdx.x * 256 + threadIdx.x;
  if (g >= n) return;
  unsigned long long bal = __ballot(m[g] != 0);
  int lane = threadIdx.x & 63;
  if (lane == 0) w[g >> 5] = (uint32_t)bal;
  else if (lane == 32) w[g >> 5] = (uint32_t)(bal >> 32);
}

// ---------------- GEMM core v4: 3-deep LDS ring, counted vmcnt ----------------
// 128x128 tile, 4 waves 2x2. Unit = BK=32 K-slice (A 8KB + B 8KB = 16KB).
// Ring of 3 units (48KB LDS -> 3 blocks/CU). Stage unit u+3 into buf u%3
// right after all waves finish reading it. Steady vmcnt(8) = 2 units in
// flight; tail 8/4/0. Per-wave vmcnt guards own loads; barrier joins waves.
// K is fixed at 1024 (32 units) for both call sites.

#define GS(U, BUF)                                                   \
  {                                                                  \
    char* dA_ = lds + (BUF) * 16384 + (w << 11);                     \
    const u16* a_ = As + ((U) << 5);                                 \
    const u16* b_ = Bs + ((U) << 5);                                 \
    gld_lds16(a_, dA_);                                              \
    gld_lds16(a_ + (K << 4), dA_ + 1024);                            \
    gld_lds16(b_, dA_ + 8192);                                       \
    gld_lds16(b_ + (K << 4), dA_ + 9216);                            \
  }

#define PH(U, BUF, DOSTAGE, VMS)                                                          \
  {                                                                                       \
    asm volatile("s_waitcnt vmcnt(" VMS ")" ::: "memory");                                \
    __builtin_amdgcn_sched_barrier(0);                                                    \
    __builtin_amdgcn_s_barrier();                                                         \
    __builtin_amdgcn_sched_barrier(0);                                                    \
    const char* rb_ = lds + (BUF) * 16384;                                                \
    short8 af[4], bfr[4];                                                                 \
    _Pragma("unroll")                                                                     \
    for (int mi = 0; mi < 4; ++mi) {                                                      \
      int row = wm * 64 + mi * 16 + lr;                                                   \
      af[mi] = *(const short8*)(rb_ + row * 64 + ((lg ^ ((row >> 1) & 3)) << 4));         \
    }                                                                                     \
    _Pragma("unroll")                                                                     \
    for (int ni = 0; ni < 4; ++ni) {                                                      \
      int row = wn * 64 + ni * 16 + lr;                                                   \
      bfr[ni] = *(const short8*)(rb_ + 8192 + row * 64 + ((lg ^ ((row >> 1) & 3)) << 4)); \
    }                                                                                     \
    asm volatile("s_waitcnt lgkmcnt(0)" ::: "memory");                                    \
    __builtin_amdgcn_sched_barrier(0);                                                    \
    __builtin_amdgcn_s_barrier();                                                         \
    __builtin_amdgcn_sched_barrier(0);                                                    \
    if (DOSTAGE) GS((U) + 3, BUF);                                                        \
    __builtin_amdgcn_s_setprio(1);                                                        \
    _Pragma("unroll")                                                                     \
    for (int mi = 0; mi < 4; ++mi)                                                        \
      _Pragma("unroll")                                                                   \
      for (int ni = 0; ni < 4; ++ni)                                                      \
        acc[mi][ni] =                                                                     \
            __builtin_amdgcn_mfma_f32_16x16x32_bf16(af[mi], bfr[ni], acc[mi][ni], 0, 0, 0); \
    __builtin_amdgcn_s_setprio(0);                                                        \
  }

__device__ __forceinline__ void gemm_core(const u16* __restrict__ A,
                                          const u16* __restrict__ Bt,
                                          int K, int m0, int n0,
                                          f32x4 (&acc)[4][4], char* lds) {
  const int t = threadIdx.x;
  const int l = t & 63;
  const int w = t >> 6;
  const int wm = w >> 1, wn = w & 1;
  const int lr = l & 15, lg = l >> 4;
  const int r0 = (w << 5) + (l >> 2);
  const int c = (l & 3) ^ ((r0 >> 1) & 3);
  const u16* As = A + (size_t)(m0 + r0) * K + c * 8;
  const u16* Bs = Bt + (size_t)(n0 + r0) * K + c * 8;

  GS(0, 0);
  GS(1, 1);
  GS(2, 2);

#pragma unroll 1
  for (int i = 0; i < 9; ++i) {
    const int u = 3 * i;
    PH(u + 0, 0, true, "8");
    PH(u + 1, 1, true, "8");
    PH(u + 2, 2, true, "8");
  }
  PH(27, 0, true, "8");
  PH(28, 1, true, "8");
  PH(29, 2, false, "8");
  PH(30, 0, false, "4");
  PH(31, 1, false, "0");
}

__global__ __launch_bounds__(256, 3) void k_gemm_qkv(const u16* __restrict__ xb,
                                                     const u16* __restrict__ wqT,
                                                     u16* __restrict__ Qb,
                                                     u16* __restrict__ Kb,
                                                     u16* __restrict__ VT) {
  __shared__ char lds[49152] __attribute__((aligned(128)));
  int n0 = blockIdx.x * 128, m0 = blockIdx.y * 128;
  f32x4 acc[4][4] = {};
  gemm_core(xb, wqT, 1024, m0, n0, acc, lds);
  const int l = threadIdx.x & 63, w = threadIdx.x >> 6;
  const int wm = w >> 1, wn = w & 1;
  const int lr = l & 15, lg = l >> 4;
#pragma unroll
  for (int mi = 0; mi < 4; ++mi)
#pragma unroll
    for (int ni = 0; ni < 4; ++ni)
#pragma unroll
      for (int r = 0; r < 4; ++r) {
        int m = m0 + wm * 64 + mi * 16 + lg * 4 + r;
        int n = n0 + wn * 64 + ni * 16 + lr;
        int b = m >> 11, seq = m & 2047;
        float av = acc[mi][ni][r];
        if (n < 1024) {
          // Q pre-scaled by SCALE*log2(e): QK^T lands in log2 domain
          Qb[((size_t)((b << 4) + (n >> 6)) * 2048 + seq) * 64 + (n & 63)] = f2bf(av * K2E);
        } else if (n < 2048) {
          int nn = n - 1024;
          Kb[((size_t)((b << 4) + (nn >> 6)) * 2048 + seq) * 64 + (nn & 63)] = f2bf(av);
        } else {
          int nn = n - 2048;
          VT[((size_t)((b << 4) + (nn >> 6)) * 64 + (nn & 63)) * 2048 + seq] = f2bf(av);
        }
      }
}

__global__ __launch_bounds__(256, 3) void k_gemm_out(const u16* __restrict__ ao,
                                                     const u16* __restrict__ woT,
                                                     const float* __restrict__ bias,
                                                     float* __restrict__ out) {
  __shared__ char lds[49152] __attribute__((aligned(128)));
  int n0 = blockIdx.x * 128, m0 = blockIdx.y * 128;
  f32x4 acc[4][4] = {};
  gemm_core(ao, woT, 1024, m0, n0, acc, lds);
  const int l = threadIdx.x & 63, w = threadIdx.x >> 6;
  const int wm = w >> 1, wn = w & 1;
  const int lr = l & 15, lg = l >> 4;
#pragma unroll
  for (int mi = 0; mi < 4; ++mi)
#pragma unroll
    for (int ni = 0; ni < 4; ++ni)
#pragma unroll
      for (int r = 0; r < 4; ++r) {
        int m = m0 + wm * 64 + mi * 16 + lg * 4 + r;
        int n = n0 + wn * 64 + ni * 16 + lr;
        out[(size_t)m * 1024 + n] = acc[mi][ni][r] + bias[n];
      }
}

// ---------------- flash attention v5 ----------------
// v4 + : Q pre-scaled (no K2E mul), mask = sbfe+bfi (2 ops/elem),
// l-row-sum via ones-MFMA (A = all-1.0) accumulated alongside PV.
__global__ __launch_bounds__(512, 4) void k_attn(const u16* __restrict__ Qg,
                                                 const u16* __restrict__ Kg,
                                                 const u16* __restrict__ Vg,
                                                 const uint32_t* __restrict__ maskw,
                                                 u16* __restrict__ AO) {
  __shared__ char lds[65536] __attribute__((aligned(128)));
  const int bid = blockIdx.x;
  const int qt = bid & 15;
  const int hd = (bid >> 4) & 15;
  const int b = bid >> 8;
  const int bh = (b << 4) + hd;
  const int tx = threadIdx.x, l = tx & 63, w = tx >> 6;
  const int wq = w & 3, kvh = w >> 2;
  const int l31 = l & 31, h = l >> 5;
  const int hx4 = (h ^ (l & 7)) << 4;
  const int sc8 = ((l & 7) ^ (l >> 3)) << 3;
  const int lr8 = l >> 3;

  const u16* Qp = Qg + (size_t)bh * 131072;
  const int q = qt * 128 + wq * 32 + l31;
  const int kv0 = kvh << 10;

  const u16* kg = Kg + (size_t)bh * 131072 + (size_t)(kv0 + 16 * wq + lr8) * 64 + sc8;
  const u16* vg = Vg + (size_t)bh * 131072 + (size_t)(16 * wq + lr8) * 2048 + kv0 + sc8;
  const uint2v* mp = (const uint2v*)(maskw + ((size_t)(b << 11) + q) * 64) + (kvh << 4);

  short8 qf[4];
#pragma unroll
  for (int s = 0; s < 4; ++s)
    qf[s] = *(const short8*)(Qp + (size_t)q * 64 + s * 16 + h * 8);

  const short8 ones8 = {0x3F80, 0x3F80, 0x3F80, 0x3F80, 0x3F80, 0x3F80, 0x3F80, 0x3F80};
  f32x16 Oa[2] = {};
  f32x16 acc_l = {};
  char* ldsH = lds + (kvh << 15);

#define STAGE(BSEL, TT)                                       \
  {                                                           \
    char* base_ = ldsH + (BSEL) * 16384 + (wq << 11);         \
    const u16* k_ = kg + ((size_t)(TT) << 12);                \
    const u16* v_ = vg + ((size_t)(TT) << 6);                 \
    gld_lds16(k_, base_);                                     \
    gld_lds16(k_ + 512, base_ + 1024);                        \
    gld_lds16(v_, base_ + 8192);                              \
    gld_lds16(v_ + 16384, base_ + 9216);                      \
  }

  STAGE(0, 0);

#pragma unroll 1
  for (int tt = 0; tt < 16; ++tt) {
    __syncthreads();
    if (tt + 1 < 16) STAGE((tt + 1) & 1, tt + 1);
    const uint2v mm = mp[tt];
    const char* kbase = ldsH + (tt & 1) * 16384 + l31 * 128;
    const char* vbase = kbase + 8192;

    f32x16 sa = {}, sb = {};
    __builtin_amdgcn_s_setprio(1);
#pragma unroll
    for (int s = 0; s < 4; ++s) {
      short8 k0 = *(const short8*)(kbase + ((s << 5) ^ hx4));
      short8 k1 = *(const short8*)(kbase + 4096 + ((s << 5) ^ hx4));
      sa = __builtin_amdgcn_mfma_f32_32x32x16_bf16(k0, qf[s], sa, 0, 0, 0);
      sb = __builtin_amdgcn_mfma_f32_32x32x16_bf16(k1, qf[s], sb, 0, 0, 0);
    }
    __builtin_amdgcn_s_setprio(0);

    // p = 2^s (s already log2-scaled via Q); zero masked via sbfe+bfi
    const uint32_t zm0 = mm.x >> (4 * h);
    const uint32_t zm1 = mm.y >> (4 * h);
#pragma unroll
    for (int r = 0; r < 16; ++r) {
      const int oc = (r & 3) + 8 * (r >> 2);
      sa[r] = mask_zero(exp2a(sa[r]), zm0, oc);
      sb[r] = mask_zero(exp2a(sb[r]), zm1, oc);
    }

    short8 pf[4];
    pack_frags(sa, pf[0], pf[1]);
    pack_frags(sb, pf[2], pf[3]);

    // O^T += V^T @ P^T ; l += 1-vec @ P^T (row-sum on the MFMA pipe)
    __builtin_amdgcn_s_setprio(1);
#pragma unroll
    for (int cc = 0; cc < 4; ++cc) {
      short8 v0 = *(const short8*)(vbase + ((cc << 5) ^ hx4));
      short8 v1 = *(const short8*)(vbase + 4096 + ((cc << 5) ^ hx4));
      Oa[0] = __builtin_amdgcn_mfma_f32_32x32x16_bf16(v0, pf[cc], Oa[0], 0, 0, 0);
      Oa[1] = __builtin_amdgcn_mfma_f32_32x32x16_bf16(v1, pf[cc], Oa[1], 0, 0, 0);
      acc_l = __builtin_amdgcn_mfma_f32_32x32x16_bf16(ones8, pf[cc], acc_l, 0, 0, 0);
    }
    __builtin_amdgcn_s_setprio(0);
  }
#undef STAGE

  // ---- merge kv-halves: O = (O0+O1)/(l0+l1) ----
  __syncthreads();
  float* cb = (float*)lds;
  if (kvh) {
#pragma unroll
    for (int r = 0; r < 32; ++r)
      cb[((wq << 5) + r) * 64 + l] = Oa[r >> 4][r & 15];
    cb[8192 + (wq << 6) + l] = acc_l[0];
  }
  __syncthreads();
  if (!kvh) {
#pragma unroll
    for (int r = 0; r < 32; ++r)
      Oa[r >> 4][r & 15] += cb[((wq << 5) + r) * 64 + l];
    float lt = acc_l[0] + cb[8192 + (wq << 6) + l];
    float inv = 1.0f / fmaxf(lt, 1e-30f);
    u16* orow = AO + ((size_t)(b << 11) + q) * 1024 + hd * 64 + h * 4;
#pragma unroll
    for (int dt = 0; dt < 2; ++dt)
#pragma unroll
      for (int rq = 0; rq < 4; ++rq) {
        uint32_t w0 = cvtpk(Oa[dt][4 * rq + 0] * inv, Oa[dt][4 * rq + 1] * inv);
        uint32_t w1 = cvtpk(Oa[dt][4 * rq + 2] * inv, Oa[dt][4 * rq + 3] * inv);
        *(uint32_t*)(orow + dt * 32 + rq * 8) = w0;
        *(uint32_t*)(orow + dt * 32 + rq * 8 + 2) = w1;
      }
  }
}

// ---------------- launch ----------------

extern "C" void kernel_launch(void* const* d_in, const int* in_sizes, int n_in,
                              void* d_out, int out_size, void* d_ws, size_t ws_size,
                              hipStream_t stream) {
  const float* x = (const float*)d_in[0];
  const int* mask = (const int*)d_in[1];
  const float* Wqkv = (const float*)d_in[2];
  const float* Wout = (const float*)d_in[3];
  const float* bout = (const float*)d_in[4];
  float* out = (float*)d_out;
  char* ws = (char*)d_ws;
  const size_t MB = 1u << 20;
  if (ws_size < 49 * MB) return;

  u16* xb = (u16*)(ws);                     // 8 MB  [4096][1024]
  u16* wqT = (u16*)(ws + 8 * MB);           // 6 MB  [3072][1024]
  u16* woT = (u16*)(ws + 14 * MB);          // 2 MB  [1024][1024]
  uint32_t* mw = (uint32_t*)(ws + 16 * MB); // 1 MB  [B][2048][64]
  u16* Qb = (u16*)(ws + 17 * MB);           // 8 MB  [B,H,2048,64]
  u16* Kb = (u16*)(ws + 25 * MB);           // 8 MB  [B,H,2048,64]
  u16* VT = (u16*)(ws + 33 * MB);           // 8 MB  [B,H,64,2048]
  u16* AO = (u16*)(ws + 41 * MB);           // 8 MB  [4096][1024]

  k_cvt_x<<<4096, 256, 0, stream>>>(x, xb, 1048576);
  k_transpose_bf<<<dim3(96, 32), dim3(32, 8), 0, stream>>>(Wqkv, wqT, 1024, 3072);
  k_transpose_bf<<<dim3(32, 32), dim3(32, 8), 0, stream>>>(Wout, woT, 1024, 1024);
  k_mask_pack<<<32768, 256, 0, stream>>>(mask, mw, 8388608);
  k_gemm_qkv<<<dim3(24, 32), 256, 0, stream>>>(xb, wqT, Qb, Kb, VT);
  k_attn<<<512, 512, 0, stream>>>(Qb, Kb, VT, mw, AO);
  k_gemm_out<<<dim3(8, 32), 256, 0, stream>>>(AO, woT, bout, out);
}